// Round 6
// baseline (1264.884 us; speedup 1.0000x reference)
//
#include <hip/hip_runtime.h>

// Problem constants (fixed by the reference)
constexpr int Nn  = 100000;   // nodes
constexpr int Ee  = 1600000;  // edges
constexpr int FIN = 128;      // input features
constexpr int Hh  = 32;       // hidden
constexpr int Cc  = 10;       // classes
constexpr int Gg  = 256;      // graphs

// Atomic-free scatter/histogram partitioning: 64 blocks, each owns a disjoint
// node range whose CSR cursors live in LDS. Correct regardless of XCD mapping.
constexpr int SBLK = 64;
constexpr int SRNG = (Nn + SBLK - 1) / SBLK;   // 1563 nodes per block

__device__ __forceinline__ void atomAddF(float* p, float v) {
    unsafeAtomicAdd(p, v);    // HW global_atomic_add_f32 on gfx950
}

// ---------- degree via LDS histogram (no global atomics) ----------
__global__ __launch_bounds__(512) void k_deg2(const int* __restrict__ dst,
                                              int* __restrict__ deg) {
    __shared__ int hist[SRNG];
    int b = blockIdx.x;
    int lo = b * SRNG;
    int hi = min(lo + SRNG, Nn);
    int cnt = hi - lo;
    for (int i = threadIdx.x; i < cnt; i += 512) hist[i] = 0;
    __syncthreads();
    const int4* d4 = reinterpret_cast<const int4*>(dst);
    const int E4 = Ee / 4;
    for (int i = threadIdx.x; i < E4; i += 512) {
        int4 d = d4[i];
        if (d.x >= lo && d.x < hi) atomicAdd(&hist[d.x - lo], 1);
        if (d.y >= lo && d.y < hi) atomicAdd(&hist[d.y - lo], 1);
        if (d.z >= lo && d.z < hi) atomicAdd(&hist[d.z - lo], 1);
        if (d.w >= lo && d.w < hi) atomicAdd(&hist[d.w - lo], 1);
    }
    __syncthreads();
    for (int i = threadIdx.x; i < cnt; i += 512) deg[lo + i] = hist[i];
}

__global__ __launch_bounds__(256) void k_dinv(const int* __restrict__ deg, float* __restrict__ dinv) {
    int n = blockIdx.x * 256 + threadIdx.x;
    if (n < Nn) dinv[n] = rsqrtf((float)deg[n] + 1.0f);
}

// ---------- exclusive scan of deg -> rowptr (3 phases) ----------
__global__ __launch_bounds__(256) void k_scan1(const int* __restrict__ deg,
                                               int* __restrict__ rowptr,
                                               int* __restrict__ bsum) {
    __shared__ int sh[256];
    int t = threadIdx.x;
    int base = blockIdx.x * 1024 + t * 4;
    int v0 = (base + 0 < Nn) ? deg[base + 0] : 0;
    int v1 = (base + 1 < Nn) ? deg[base + 1] : 0;
    int v2 = (base + 2 < Nn) ? deg[base + 2] : 0;
    int v3 = (base + 3 < Nn) ? deg[base + 3] : 0;
    int s = v0 + v1 + v2 + v3;
    sh[t] = s;
    __syncthreads();
    for (int off = 1; off < 256; off <<= 1) {
        int x = (t >= off) ? sh[t - off] : 0;
        __syncthreads();
        sh[t] += x;
        __syncthreads();
    }
    int excl = sh[t] - s;
    if (t == 255) bsum[blockIdx.x] = sh[255];
    if (base + 0 < Nn) rowptr[base + 0] = excl;
    if (base + 1 < Nn) rowptr[base + 1] = excl + v0;
    if (base + 2 < Nn) rowptr[base + 2] = excl + v0 + v1;
    if (base + 3 < Nn) rowptr[base + 3] = excl + v0 + v1 + v2;
}

__global__ __launch_bounds__(256) void k_scan2(int* __restrict__ bsum, int NB) {
    __shared__ int sh[256];
    int t = threadIdx.x;
    int v = (t < NB) ? bsum[t] : 0;
    sh[t] = v;
    __syncthreads();
    for (int off = 1; off < 256; off <<= 1) {
        int x = (t >= off) ? sh[t - off] : 0;
        __syncthreads();
        sh[t] += x;
        __syncthreads();
    }
    if (t < NB) bsum[t] = sh[t] - v;
}

__global__ __launch_bounds__(256) void k_scan3(int* __restrict__ rowptr,
                                               const int* __restrict__ bsum) {
    int i = blockIdx.x * 256 + threadIdx.x;
    if (i < Nn) rowptr[i] += bsum[i >> 10];
}

// ---------- atomic-free scatter: LDS cursors per node range ----------
// Block b owns nodes [b*SRNG, b*SRNG+SRNG); streams the whole dst array
// (int4), in-range edges take a slot from an LDS cursor (ds_add_rtn) and
// store src into the block's private contiguous CSR region. Zero global
// atomics; disjoint ranges -> no cross-block races.
__global__ __launch_bounds__(512) void k_scatter2(const int* __restrict__ src,
                                                  const int* __restrict__ dst,
                                                  const int* __restrict__ rowptr,
                                                  int* __restrict__ csr) {
    __shared__ int lcur[SRNG];
    int b = blockIdx.x;
    int lo = b * SRNG;
    int hi = min(lo + SRNG, Nn);
    int cnt = hi - lo;
    for (int i = threadIdx.x; i < cnt; i += 512) lcur[i] = rowptr[lo + i];
    __syncthreads();
    const int4* d4 = reinterpret_cast<const int4*>(dst);
    const int E4 = Ee / 4;
    for (int i = threadIdx.x; i < E4; i += 512) {
        int4 d = d4[i];
        int e = 4 * i;
        if (d.x >= lo && d.x < hi) { int slot = atomicAdd(&lcur[d.x - lo], 1); csr[slot] = src[e + 0]; }
        if (d.y >= lo && d.y < hi) { int slot = atomicAdd(&lcur[d.y - lo], 1); csr[slot] = src[e + 1]; }
        if (d.z >= lo && d.z < hi) { int slot = atomicAdd(&lcur[d.z - lo], 1); csr[slot] = src[e + 2]; }
        if (d.w >= lo && d.w < hi) { int slot = atomicAdd(&lcur[d.w - lo], 1); csr[slot] = src[e + 3]; }
    }
}

// ---------- dense layers (output pre-scaled by dinv[row]) ----------
__global__ __launch_bounds__(256) void k_gemm128(const float* __restrict__ x,
                                                 const float* __restrict__ W,
                                                 const float* __restrict__ dinv,
                                                 float* __restrict__ hls) {
    __shared__ float ws[FIN * Hh];
    int tid = threadIdx.x;
#pragma unroll
    for (int i = 0; i < (FIN * Hh) / 256; ++i) ws[tid + 256 * i] = W[tid + 256 * i];
    __syncthreads();
    int row = blockIdx.x * 8 + (tid >> 5);
    int col = tid & 31;
    if (row >= Nn) return;
    const float4* x4 = reinterpret_cast<const float4*>(x + (size_t)row * FIN);
    float acc = 0.f;
#pragma unroll
    for (int k4 = 0; k4 < FIN / 4; ++k4) {
        float4 xv = x4[k4];
        acc = fmaf(xv.x, ws[(4 * k4 + 0) * Hh + col], acc);
        acc = fmaf(xv.y, ws[(4 * k4 + 1) * Hh + col], acc);
        acc = fmaf(xv.z, ws[(4 * k4 + 2) * Hh + col], acc);
        acc = fmaf(xv.w, ws[(4 * k4 + 3) * Hh + col], acc);
    }
    hls[(size_t)row * Hh + col] = acc * dinv[row];
}

__global__ __launch_bounds__(256) void k_gemm32(const float* __restrict__ h,
                                                const float* __restrict__ W,
                                                const float* __restrict__ dinv,
                                                float* __restrict__ hls) {
    __shared__ float ws[Hh * Hh];
    int tid = threadIdx.x;
    ws[tid]       = W[tid];
    ws[tid + 256] = W[tid + 256];
    ws[tid + 512] = W[tid + 512];
    ws[tid + 768] = W[tid + 768];
    __syncthreads();
    int row = blockIdx.x * 8 + (tid >> 5);
    int col = tid & 31;
    if (row >= Nn) return;
    const float4* h4 = reinterpret_cast<const float4*>(h + (size_t)row * Hh);
    float acc = 0.f;
#pragma unroll
    for (int k4 = 0; k4 < Hh / 4; ++k4) {
        float4 hv = h4[k4];
        acc = fmaf(hv.x, ws[(4 * k4 + 0) * Hh + col], acc);
        acc = fmaf(hv.y, ws[(4 * k4 + 1) * Hh + col], acc);
        acc = fmaf(hv.z, ws[(4 * k4 + 2) * Hh + col], acc);
        acc = fmaf(hv.w, ws[(4 * k4 + 3) * Hh + col], acc);
    }
    hls[(size_t)row * Hh + col] = acc * dinv[row];
}

// ---------- fused aggregation: gather CSR + self loop + bias + relu ----------
__global__ __launch_bounds__(256) void k_agg(const float* __restrict__ hls,
                                             const int* __restrict__ csr,
                                             const int* __restrict__ rowptr,
                                             const int* __restrict__ deg,
                                             const float* __restrict__ dinv,
                                             const float* __restrict__ b,
                                             float* __restrict__ hout) {
    long long t = (long long)blockIdx.x * 256 + threadIdx.x;
    int n = (int)(t >> 5);
    int col = (int)(t & 31);
    if (n >= Nn) return;
    int beg = rowptr[n];
    int end = beg + deg[n];
    float acc = 0.f;
    for (int i = beg; i < end; i += 8) {
        int   idx[8];
        float msk[8];
#pragma unroll
        for (int j = 0; j < 8; ++j) {
            int k = i + j;
            int c = csr[k];                 // csr padded by 8 -> always in-bounds
            bool m = (k < end);
            idx[j] = m ? c : n;             // safe gather target when masked
            msk[j] = m ? 1.f : 0.f;
        }
        float v[8];
#pragma unroll
        for (int j = 0; j < 8; ++j) v[j] = hls[(size_t)idx[j] * Hh + col];
#pragma unroll
        for (int j = 0; j < 8; ++j) acc = fmaf(msk[j], v[j], acc);
    }
    float self = hls[(size_t)n * Hh + col];
    float o = fmaf(dinv[n], acc + self, b[col]);
    hout[(size_t)n * Hh + col] = fmaxf(o, 0.f);
}

// ---------- segmented mean-pool (batch is sorted) ----------
constexpr int CH = 256;  // nodes per wave
__global__ __launch_bounds__(256) void k_pool(const float* __restrict__ h,
                                              const int* __restrict__ batch,
                                              float* __restrict__ pooled,
                                              int* __restrict__ cnt) {
    int wid = (blockIdx.x * 256 + threadIdx.x) >> 6;
    int lane = threadIdx.x & 63;
    int col = lane & 31;
    int sub = lane >> 5;
    int n0 = wid * CH;
    if (n0 >= Nn) return;
    int nEnd = min(n0 + CH, Nn);
    float acc = 0.f;
    int gcur = -1, cntLoc = 0;
    for (int n = n0 + sub; n < nEnd; n += 2) {
        int g = batch[n];
        if (g != gcur) {
            if (gcur >= 0) {
                atomAddF(&pooled[gcur * Hh + col], acc);
                if (col == 0) atomicAdd(&cnt[gcur], cntLoc);
            }
            acc = 0.f; cntLoc = 0; gcur = g;
        }
        acc += h[(size_t)n * Hh + col];
        cntLoc++;
    }
    if (gcur >= 0) {
        atomAddF(&pooled[gcur * Hh + col], acc);
        if (col == 0) atomicAdd(&cnt[gcur], cntLoc);
    }
}

// ---------- MLP head + log_softmax ----------
__global__ __launch_bounds__(256) void k_head(const float* __restrict__ pooled,
                                              const int* __restrict__ cnt,
                                              const float* __restrict__ Wf1,
                                              const float* __restrict__ bf1,
                                              const float* __restrict__ Wf2,
                                              const float* __restrict__ bf2,
                                              float* __restrict__ out) {
    __shared__ float w1[Hh * Hh];
    __shared__ float w2[Hh * Cc];
    __shared__ float sb1[Hh];
    __shared__ float sb2[Cc];
    int tid = threadIdx.x;
    w1[tid] = Wf1[tid]; w1[tid + 256] = Wf1[tid + 256];
    w1[tid + 512] = Wf1[tid + 512]; w1[tid + 768] = Wf1[tid + 768];
    for (int i = tid; i < Hh * Cc; i += 256) w2[i] = Wf2[i];
    if (tid < Hh) sb1[tid] = bf1[tid];
    if (tid < Cc) sb2[tid] = bf2[tid];
    __syncthreads();

    int g = tid;
    float inv = 1.0f / fmaxf((float)cnt[g], 1.0f);
    float p[Hh];
#pragma unroll
    for (int c = 0; c < Hh; ++c) p[c] = pooled[g * Hh + c] * inv;
    float h1[Hh];
#pragma unroll
    for (int j = 0; j < Hh; ++j) {
        float acc = sb1[j];
#pragma unroll
        for (int k = 0; k < Hh; ++k) acc = fmaf(p[k], w1[k * Hh + j], acc);
        h1[j] = fmaxf(acc, 0.f);
    }
    float lg[Cc];
#pragma unroll
    for (int j = 0; j < Cc; ++j) {
        float acc = sb2[j];
#pragma unroll
        for (int k = 0; k < Hh; ++k) acc = fmaf(h1[k], w2[k * Cc + j], acc);
        lg[j] = acc;
    }
    float m = lg[0];
#pragma unroll
    for (int j = 1; j < Cc; ++j) m = fmaxf(m, lg[j]);
    float s = 0.f;
#pragma unroll
    for (int j = 0; j < Cc; ++j) s += __expf(lg[j] - m);
    float lse = m + __logf(s);
#pragma unroll
    for (int j = 0; j < Cc; ++j) out[g * Cc + j] = lg[j] - lse;
}

extern "C" void kernel_launch(void* const* d_in, const int* in_sizes, int n_in,
                              void* d_out, int out_size, void* d_ws, size_t ws_size,
                              hipStream_t stream) {
    const float* x    = (const float*)d_in[0];
    const int*   ei   = (const int*)d_in[1];   // [2, E] -> src = ei, dst = ei + E
    const int*   batch= (const int*)d_in[2];
    const float* W1   = (const float*)d_in[3];
    const float* b1   = (const float*)d_in[4];
    const float* W2   = (const float*)d_in[5];
    const float* b2   = (const float*)d_in[6];
    const float* W3   = (const float*)d_in[7];
    const float* b3   = (const float*)d_in[8];
    const float* W4   = (const float*)d_in[9];
    const float* b4   = (const float*)d_in[10];
    const float* Wf1  = (const float*)d_in[11];
    const float* bf1  = (const float*)d_in[12];
    const float* Wf2  = (const float*)d_in[13];
    const float* bf2  = (const float*)d_in[14];
    float* out = (float*)d_out;

    const int* src = ei;
    const int* dst = ei + Ee;

    // Workspace layout (8B-aligned first)
    char* ws = (char*)d_ws;
    float* hl     = (float*)ws;   ws += sizeof(float) * Nn * Hh;   // hls (scaled)
    float* hbuf   = (float*)ws;   ws += sizeof(float) * Nn * Hh;
    int*   csr    = (int*)ws;     ws += sizeof(int) * (Ee + 8);    // +8 pad for masked tail
    int*   rowptr = (int*)ws;     ws += sizeof(int) * Nn;
    int*   deg    = (int*)ws;     ws += sizeof(int) * Nn;
    float* dinv   = (float*)ws;   ws += sizeof(float) * Nn;
    int*   bsum   = (int*)ws;     ws += sizeof(int) * 256;
    float* pooled = (float*)ws;   ws += sizeof(float) * Gg * Hh;
    int*   cnt    = (int*)ws;     ws += sizeof(int) * Gg;

    const int nbNodeCol = (Nn * Hh + 255) / 256;           // 12500
    const int nbRows    = (Nn + 7) / 8;                    // 12500
    const int NB1       = (Nn + 1023) / 1024;              // 98

    // ---- graph preprocessing: degrees, dinv, CSR (no global atomics) ----
    k_deg2<<<SBLK, 512, 0, stream>>>(dst, deg);
    k_dinv<<<(Nn + 255) / 256, 256, 0, stream>>>(deg, dinv);
    k_scan1<<<NB1, 256, 0, stream>>>(deg, rowptr, bsum);
    k_scan2<<<1, 256, 0, stream>>>(bsum, NB1);
    k_scan3<<<(Nn + 255) / 256, 256, 0, stream>>>(rowptr, bsum);
    k_scatter2<<<SBLK, 512, 0, stream>>>(src, dst, rowptr, csr);

    // ---- layer 1 ----
    k_gemm128<<<nbRows, 256, 0, stream>>>(x, W1, dinv, hl);
    k_agg<<<nbNodeCol, 256, 0, stream>>>(hl, csr, rowptr, deg, dinv, b1, hbuf);

    // ---- layers 2..4 ----
    const float* Wsv[3] = {W2, W3, W4};
    const float* bsv[3] = {b2, b3, b4};
    for (int l = 0; l < 3; ++l) {
        k_gemm32<<<nbRows, 256, 0, stream>>>(hbuf, Wsv[l], dinv, hl);
        k_agg<<<nbNodeCol, 256, 0, stream>>>(hl, csr, rowptr, deg, dinv, bsv[l], hbuf);
    }

    // ---- pool + head ----
    hipMemsetAsync(pooled, 0, sizeof(float) * Gg * Hh, stream);
    hipMemsetAsync(cnt, 0, sizeof(int) * Gg, stream);
    {
        int waves = (Nn + CH - 1) / CH;
        int blocks = (waves * 64 + 255) / 256;
        k_pool<<<blocks, 256, 0, stream>>>(hbuf, batch, pooled, cnt);
    }
    k_head<<<1, 256, 0, stream>>>(pooled, cnt, Wf1, bf1, Wf2, bf2, out);
}

// Round 7
// 348.529 us; speedup vs baseline: 3.6292x; 3.6292x over previous
//
#include <hip/hip_runtime.h>

// Problem constants (fixed by the reference)
constexpr int Nn  = 100000;   // nodes
constexpr int Ee  = 1600000;  // edges
constexpr int FIN = 128;      // input features
constexpr int Hh  = 32;       // hidden
constexpr int Cc  = 10;       // classes
constexpr int Gg  = 256;      // graphs

// Two-level counting sort: ranges of 256 nodes, chunks of 8192 edges.
constexpr int RSH  = 8;                          // range shift (256 nodes)
constexpr int NR   = (Nn + 255) >> RSH;          // 391 ranges
constexpr int CHSZ = 8192;                       // edges per chunk
constexpr int NCH  = (Ee + CHSZ - 1) / CHSZ;     // 196 chunks

__device__ __forceinline__ void atomAddF(float* p, float v) {
    unsafeAtomicAdd(p, v);    // HW global_atomic_add_f32 on gfx950
}

// ---------- S1: per-chunk histogram over node ranges ----------
__global__ __launch_bounds__(512) void k_count(const int* __restrict__ dst,
                                               int* __restrict__ M) {
    __shared__ int hist[NR];
    int c = blockIdx.x;
    for (int i = threadIdx.x; i < NR; i += 512) hist[i] = 0;
    __syncthreads();
    int e0 = c * CHSZ, e1 = min(e0 + CHSZ, Ee);
    const int4* d4 = reinterpret_cast<const int4*>(dst + e0);
    int n4 = (e1 - e0) >> 2;
    for (int i = threadIdx.x; i < n4; i += 512) {
        int4 d = d4[i];
        atomicAdd(&hist[d.x >> RSH], 1);
        atomicAdd(&hist[d.y >> RSH], 1);
        atomicAdd(&hist[d.z >> RSH], 1);
        atomicAdd(&hist[d.w >> RSH], 1);
    }
    __syncthreads();
    for (int i = threadIdx.x; i < NR; i += 512) M[c * NR + i] = hist[i];
}

// ---------- S2a: per-range exclusive scan over chunks (in place), totals -> T
__global__ __launch_bounds__(256) void k_scanM(int* __restrict__ M,
                                               int* __restrict__ T) {
    __shared__ int sh[256];
    int t = threadIdx.x, r = blockIdx.x;
    int v = (t < NCH) ? M[t * NR + r] : 0;
    sh[t] = v;
    __syncthreads();
    for (int off = 1; off < 256; off <<= 1) {
        int x = (t >= off) ? sh[t - off] : 0;
        __syncthreads();
        sh[t] += x;
        __syncthreads();
    }
    if (t < NCH) M[t * NR + r] = sh[t] - v;   // exclusive
    if (t == 255) T[r] = sh[255];
}

// ---------- S2b: exclusive scan of range totals -> R (R[NR] = Ee) ----------
__global__ __launch_bounds__(512) void k_scanT(const int* __restrict__ T,
                                               int* __restrict__ R) {
    __shared__ int sh[512];
    int t = threadIdx.x;
    int v = (t < NR) ? T[t] : 0;
    sh[t] = v;
    __syncthreads();
    for (int off = 1; off < 512; off <<= 1) {
        int x = (t >= off) ? sh[t - off] : 0;
        __syncthreads();
        sh[t] += x;
        __syncthreads();
    }
    if (t < NR) R[t] = sh[t] - v;
    if (t == 511) R[NR] = sh[511];
}

// ---------- S3: scatter (src,dst) into range-grouped bucket ----------
// Block c: LDS cursors = M[c][r] + R[r]; output regions disjoint across
// blocks by construction -> plain stores, zero global atomics.
__global__ __launch_bounds__(512) void k_bucket(const int* __restrict__ src,
                                                const int* __restrict__ dst,
                                                const int* __restrict__ M,
                                                const int* __restrict__ R,
                                                int2* __restrict__ bucket) {
    __shared__ int cur[NR];
    int c = blockIdx.x;
    for (int i = threadIdx.x; i < NR; i += 512) cur[i] = M[c * NR + i] + R[i];
    __syncthreads();
    int e0 = c * CHSZ, e1 = min(e0 + CHSZ, Ee);
    const int4* d4 = reinterpret_cast<const int4*>(dst + e0);
    const int4* s4 = reinterpret_cast<const int4*>(src + e0);
    int n4 = (e1 - e0) >> 2;
    for (int i = threadIdx.x; i < n4; i += 512) {
        int4 d = d4[i];
        int4 s = s4[i];
        int sl;
        sl = atomicAdd(&cur[d.x >> RSH], 1); bucket[sl] = make_int2(s.x, d.x);
        sl = atomicAdd(&cur[d.y >> RSH], 1); bucket[sl] = make_int2(s.y, d.y);
        sl = atomicAdd(&cur[d.z >> RSH], 1); bucket[sl] = make_int2(s.z, d.z);
        sl = atomicAdd(&cur[d.w >> RSH], 1); bucket[sl] = make_int2(s.w, d.w);
    }
}

// ---------- S4: per-range CSR build + deg + dinv + rowptr ----------
__global__ __launch_bounds__(512) void k_build(const int2* __restrict__ bucket,
                                               const int* __restrict__ R,
                                               int* __restrict__ csr,
                                               int* __restrict__ rowptr,
                                               int* __restrict__ deg,
                                               float* __restrict__ dinv) {
    __shared__ int hist[256];
    __shared__ int scn[256];
    __shared__ int cur[256];
    int t = threadIdx.x, r = blockIdx.x;
    int lo = r << RSH;
    int cnt = min(256, Nn - lo);
    int b0 = R[r], b1 = R[r + 1];
    if (t < 256) hist[t] = 0;
    __syncthreads();
    for (int i = b0 + t; i < b1; i += 512) {
        int2 e = bucket[i];
        atomicAdd(&hist[e.y - lo], 1);
    }
    __syncthreads();
    int hv = (t < 256) ? hist[t] : 0;
    if (t < 256) scn[t] = hv;
    __syncthreads();
    for (int off = 1; off < 256; off <<= 1) {
        int x = 0;
        if (t < 256 && t >= off) x = scn[t - off];
        __syncthreads();
        if (t < 256) scn[t] += x;
        __syncthreads();
    }
    if (t < cnt) {
        int base = b0 + (scn[t] - hv);   // exclusive within range + range start
        rowptr[lo + t] = base;
        deg[lo + t] = hv;
        dinv[lo + t] = rsqrtf((float)hv + 1.0f);
        cur[t] = base;
    }
    __syncthreads();
    for (int i = b0 + t; i < b1; i += 512) {
        int2 e = bucket[i];
        int sl = atomicAdd(&cur[e.y - lo], 1);
        csr[sl] = e.x;
    }
}

// ---------- dense layers (output pre-scaled by dinv[row]) ----------
__global__ __launch_bounds__(256) void k_gemm128(const float* __restrict__ x,
                                                 const float* __restrict__ W,
                                                 const float* __restrict__ dinv,
                                                 float* __restrict__ hls) {
    __shared__ float ws[FIN * Hh];
    int tid = threadIdx.x;
#pragma unroll
    for (int i = 0; i < (FIN * Hh) / 256; ++i) ws[tid + 256 * i] = W[tid + 256 * i];
    __syncthreads();
    int row = blockIdx.x * 8 + (tid >> 5);
    int col = tid & 31;
    if (row >= Nn) return;
    const float4* x4 = reinterpret_cast<const float4*>(x + (size_t)row * FIN);
    float acc = 0.f;
#pragma unroll
    for (int k4 = 0; k4 < FIN / 4; ++k4) {
        float4 xv = x4[k4];
        acc = fmaf(xv.x, ws[(4 * k4 + 0) * Hh + col], acc);
        acc = fmaf(xv.y, ws[(4 * k4 + 1) * Hh + col], acc);
        acc = fmaf(xv.z, ws[(4 * k4 + 2) * Hh + col], acc);
        acc = fmaf(xv.w, ws[(4 * k4 + 3) * Hh + col], acc);
    }
    hls[(size_t)row * Hh + col] = acc * dinv[row];
}

__global__ __launch_bounds__(256) void k_gemm32(const float* __restrict__ h,
                                                const float* __restrict__ W,
                                                const float* __restrict__ dinv,
                                                float* __restrict__ hls) {
    __shared__ float ws[Hh * Hh];
    int tid = threadIdx.x;
    ws[tid]       = W[tid];
    ws[tid + 256] = W[tid + 256];
    ws[tid + 512] = W[tid + 512];
    ws[tid + 768] = W[tid + 768];
    __syncthreads();
    int row = blockIdx.x * 8 + (tid >> 5);
    int col = tid & 31;
    if (row >= Nn) return;
    const float4* h4 = reinterpret_cast<const float4*>(h + (size_t)row * Hh);
    float acc = 0.f;
#pragma unroll
    for (int k4 = 0; k4 < Hh / 4; ++k4) {
        float4 hv = h4[k4];
        acc = fmaf(hv.x, ws[(4 * k4 + 0) * Hh + col], acc);
        acc = fmaf(hv.y, ws[(4 * k4 + 1) * Hh + col], acc);
        acc = fmaf(hv.z, ws[(4 * k4 + 2) * Hh + col], acc);
        acc = fmaf(hv.w, ws[(4 * k4 + 3) * Hh + col], acc);
    }
    hls[(size_t)row * Hh + col] = acc * dinv[row];
}

// ---------- fused aggregation: gather CSR + self loop + bias + relu ----------
__global__ __launch_bounds__(256) void k_agg(const float* __restrict__ hls,
                                             const int* __restrict__ csr,
                                             const int* __restrict__ rowptr,
                                             const int* __restrict__ deg,
                                             const float* __restrict__ dinv,
                                             const float* __restrict__ b,
                                             float* __restrict__ hout) {
    long long t = (long long)blockIdx.x * 256 + threadIdx.x;
    int n = (int)(t >> 5);
    int col = (int)(t & 31);
    if (n >= Nn) return;
    int beg = rowptr[n];
    int end = beg + deg[n];
    float acc = 0.f;
    for (int i = beg; i < end; i += 8) {
        int   idx[8];
        float msk[8];
#pragma unroll
        for (int j = 0; j < 8; ++j) {
            int k = i + j;
            int c = csr[k];                 // csr padded by 8 -> always in-bounds
            bool m = (k < end);
            idx[j] = m ? c : n;             // safe gather target when masked
            msk[j] = m ? 1.f : 0.f;
        }
        float v[8];
#pragma unroll
        for (int j = 0; j < 8; ++j) v[j] = hls[(size_t)idx[j] * Hh + col];
#pragma unroll
        for (int j = 0; j < 8; ++j) acc = fmaf(msk[j], v[j], acc);
    }
    float self = hls[(size_t)n * Hh + col];
    float o = fmaf(dinv[n], acc + self, b[col]);
    hout[(size_t)n * Hh + col] = fmaxf(o, 0.f);
}

// ---------- segmented mean-pool (batch is sorted) ----------
constexpr int CH = 256;  // nodes per wave
__global__ __launch_bounds__(256) void k_pool(const float* __restrict__ h,
                                              const int* __restrict__ batch,
                                              float* __restrict__ pooled,
                                              int* __restrict__ cnt) {
    int wid = (blockIdx.x * 256 + threadIdx.x) >> 6;
    int lane = threadIdx.x & 63;
    int col = lane & 31;
    int sub = lane >> 5;
    int n0 = wid * CH;
    if (n0 >= Nn) return;
    int nEnd = min(n0 + CH, Nn);
    float acc = 0.f;
    int gcur = -1, cntLoc = 0;
    for (int n = n0 + sub; n < nEnd; n += 2) {
        int g = batch[n];
        if (g != gcur) {
            if (gcur >= 0) {
                atomAddF(&pooled[gcur * Hh + col], acc);
                if (col == 0) atomicAdd(&cnt[gcur], cntLoc);
            }
            acc = 0.f; cntLoc = 0; gcur = g;
        }
        acc += h[(size_t)n * Hh + col];
        cntLoc++;
    }
    if (gcur >= 0) {
        atomAddF(&pooled[gcur * Hh + col], acc);
        if (col == 0) atomicAdd(&cnt[gcur], cntLoc);
    }
}

// ---------- MLP head + log_softmax ----------
__global__ __launch_bounds__(256) void k_head(const float* __restrict__ pooled,
                                              const int* __restrict__ cnt,
                                              const float* __restrict__ Wf1,
                                              const float* __restrict__ bf1,
                                              const float* __restrict__ Wf2,
                                              const float* __restrict__ bf2,
                                              float* __restrict__ out) {
    __shared__ float w1[Hh * Hh];
    __shared__ float w2[Hh * Cc];
    __shared__ float sb1[Hh];
    __shared__ float sb2[Cc];
    int tid = threadIdx.x;
    w1[tid] = Wf1[tid]; w1[tid + 256] = Wf1[tid + 256];
    w1[tid + 512] = Wf1[tid + 512]; w1[tid + 768] = Wf1[tid + 768];
    for (int i = tid; i < Hh * Cc; i += 256) w2[i] = Wf2[i];
    if (tid < Hh) sb1[tid] = bf1[tid];
    if (tid < Cc) sb2[tid] = bf2[tid];
    __syncthreads();

    int g = tid;
    float inv = 1.0f / fmaxf((float)cnt[g], 1.0f);
    float p[Hh];
#pragma unroll
    for (int c = 0; c < Hh; ++c) p[c] = pooled[g * Hh + c] * inv;
    float h1[Hh];
#pragma unroll
    for (int j = 0; j < Hh; ++j) {
        float acc = sb1[j];
#pragma unroll
        for (int k = 0; k < Hh; ++k) acc = fmaf(p[k], w1[k * Hh + j], acc);
        h1[j] = fmaxf(acc, 0.f);
    }
    float lg[Cc];
#pragma unroll
    for (int j = 0; j < Cc; ++j) {
        float acc = sb2[j];
#pragma unroll
        for (int k = 0; k < Hh; ++k) acc = fmaf(h1[k], w2[k * Cc + j], acc);
        lg[j] = acc;
    }
    float m = lg[0];
#pragma unroll
    for (int j = 1; j < Cc; ++j) m = fmaxf(m, lg[j]);
    float s = 0.f;
#pragma unroll
    for (int j = 0; j < Cc; ++j) s += __expf(lg[j] - m);
    float lse = m + __logf(s);
#pragma unroll
    for (int j = 0; j < Cc; ++j) out[g * Cc + j] = lg[j] - lse;
}

extern "C" void kernel_launch(void* const* d_in, const int* in_sizes, int n_in,
                              void* d_out, int out_size, void* d_ws, size_t ws_size,
                              hipStream_t stream) {
    const float* x    = (const float*)d_in[0];
    const int*   ei   = (const int*)d_in[1];   // [2, E] -> src = ei, dst = ei + E
    const int*   batch= (const int*)d_in[2];
    const float* W1   = (const float*)d_in[3];
    const float* b1   = (const float*)d_in[4];
    const float* W2   = (const float*)d_in[5];
    const float* b2   = (const float*)d_in[6];
    const float* W3   = (const float*)d_in[7];
    const float* b3   = (const float*)d_in[8];
    const float* W4   = (const float*)d_in[9];
    const float* b4   = (const float*)d_in[10];
    const float* Wf1  = (const float*)d_in[11];
    const float* bf1  = (const float*)d_in[12];
    const float* Wf2  = (const float*)d_in[13];
    const float* bf2  = (const float*)d_in[14];
    float* out = (float*)d_out;

    const int* src = ei;
    const int* dst = ei + Ee;

    // Workspace layout. bucket (int2[Ee], 12.8 MB) aliases hl: bucket is dead
    // after k_build, hl is first written by k_gemm128 (strictly after).
    char* ws = (char*)d_ws;
    float* hl     = (float*)ws;   ws += sizeof(float) * Nn * Hh;   // 12.8 MB (= bucket)
    int2*  bucket = (int2*)hl;
    float* hbuf   = (float*)ws;   ws += sizeof(float) * Nn * Hh;   // 12.8 MB
    int*   csr    = (int*)ws;     ws += sizeof(int) * (Ee + 8);    // +8 pad for masked tail
    int*   M      = (int*)ws;     ws += sizeof(int) * NCH * NR;    // 306 KB
    int*   T      = (int*)ws;     ws += sizeof(int) * NR;
    int*   R      = (int*)ws;     ws += sizeof(int) * (NR + 1);
    int*   rowptr = (int*)ws;     ws += sizeof(int) * Nn;
    int*   deg    = (int*)ws;     ws += sizeof(int) * Nn;
    float* dinv   = (float*)ws;   ws += sizeof(float) * Nn;
    float* pooled = (float*)ws;   ws += sizeof(float) * Gg * Hh;
    int*   cnt    = (int*)ws;     ws += sizeof(int) * Gg;

    const int nbNodeCol = (Nn * Hh + 255) / 256;           // 12500
    const int nbRows    = (Nn + 7) / 8;                    // 12500

    // ---- graph preprocessing: counting sort -> CSR, deg, dinv, rowptr ----
    k_count <<<NCH, 512, 0, stream>>>(dst, M);
    k_scanM <<<NR, 256, 0, stream>>>(M, T);
    k_scanT <<<1, 512, 0, stream>>>(T, R);
    k_bucket<<<NCH, 512, 0, stream>>>(src, dst, M, R, bucket);
    k_build <<<NR, 512, 0, stream>>>(bucket, R, csr, rowptr, deg, dinv);

    // ---- layer 1 ----
    k_gemm128<<<nbRows, 256, 0, stream>>>(x, W1, dinv, hl);
    k_agg<<<nbNodeCol, 256, 0, stream>>>(hl, csr, rowptr, deg, dinv, b1, hbuf);

    // ---- layers 2..4 ----
    const float* Wsv[3] = {W2, W3, W4};
    const float* bsv[3] = {b2, b3, b4};
    for (int l = 0; l < 3; ++l) {
        k_gemm32<<<nbRows, 256, 0, stream>>>(hbuf, Wsv[l], dinv, hl);
        k_agg<<<nbNodeCol, 256, 0, stream>>>(hl, csr, rowptr, deg, dinv, bsv[l], hbuf);
    }

    // ---- pool + head ----
    hipMemsetAsync(pooled, 0, sizeof(float) * Gg * Hh, stream);
    hipMemsetAsync(cnt, 0, sizeof(int) * Gg, stream);
    {
        int waves = (Nn + CH - 1) / CH;
        int blocks = (waves * 64 + 255) / 256;
        k_pool<<<blocks, 256, 0, stream>>>(hbuf, batch, pooled, cnt);
    }
    k_head<<<1, 256, 0, stream>>>(pooled, cnt, Wf1, bf1, Wf2, bf2, out);
}

// Round 8
// 301.486 us; speedup vs baseline: 4.1955x; 1.1560x over previous
//
#include <hip/hip_runtime.h>

// Problem constants (fixed by the reference)
constexpr int Nn  = 100000;   // nodes
constexpr int Ee  = 1600000;  // edges
constexpr int FIN = 128;      // input features
constexpr int Hh  = 32;       // hidden
constexpr int Cc  = 10;       // classes
constexpr int Gg  = 256;      // graphs

// Two-level counting sort: ranges of 256 nodes, chunks of 8192 edges.
constexpr int RSH  = 8;                          // range shift (256 nodes)
constexpr int NR   = (Nn + 255) >> RSH;          // 391 ranges
constexpr int CHSZ = 8192;                       // edges per chunk
constexpr int NCH  = (Ee + CHSZ - 1) / CHSZ;     // 196 chunks

__device__ __forceinline__ void atomAddF(float* p, float v) {
    unsafeAtomicAdd(p, v);    // HW global_atomic_add_f32 on gfx950
}

// ---------- S1: per-chunk histogram over node ranges ----------
__global__ __launch_bounds__(512) void k_count(const int* __restrict__ dst,
                                               int* __restrict__ M) {
    __shared__ int hist[NR];
    int c = blockIdx.x;
    for (int i = threadIdx.x; i < NR; i += 512) hist[i] = 0;
    __syncthreads();
    int e0 = c * CHSZ, e1 = min(e0 + CHSZ, Ee);
    const int4* d4 = reinterpret_cast<const int4*>(dst + e0);
    int n4 = (e1 - e0) >> 2;
    for (int i = threadIdx.x; i < n4; i += 512) {
        int4 d = d4[i];
        atomicAdd(&hist[d.x >> RSH], 1);
        atomicAdd(&hist[d.y >> RSH], 1);
        atomicAdd(&hist[d.z >> RSH], 1);
        atomicAdd(&hist[d.w >> RSH], 1);
    }
    __syncthreads();
    for (int i = threadIdx.x; i < NR; i += 512) M[c * NR + i] = hist[i];
}

// ---------- S2a: per-range exclusive scan over chunks (in place), totals -> T
__global__ __launch_bounds__(256) void k_scanM(int* __restrict__ M,
                                               int* __restrict__ T) {
    __shared__ int sh[256];
    int t = threadIdx.x, r = blockIdx.x;
    int v = (t < NCH) ? M[t * NR + r] : 0;
    sh[t] = v;
    __syncthreads();
    for (int off = 1; off < 256; off <<= 1) {
        int x = (t >= off) ? sh[t - off] : 0;
        __syncthreads();
        sh[t] += x;
        __syncthreads();
    }
    if (t < NCH) M[t * NR + r] = sh[t] - v;   // exclusive
    if (t == 255) T[r] = sh[255];
}

// ---------- S2b: exclusive scan of range totals -> R (R[NR] = Ee) ----------
__global__ __launch_bounds__(512) void k_scanT(const int* __restrict__ T,
                                               int* __restrict__ R) {
    __shared__ int sh[512];
    int t = threadIdx.x;
    int v = (t < NR) ? T[t] : 0;
    sh[t] = v;
    __syncthreads();
    for (int off = 1; off < 512; off <<= 1) {
        int x = (t >= off) ? sh[t - off] : 0;
        __syncthreads();
        sh[t] += x;
        __syncthreads();
    }
    if (t < NR) R[t] = sh[t] - v;
    if (t == 511) R[NR] = sh[511];
}

// ---------- S3: scatter (src,dst) into range-grouped bucket ----------
__global__ __launch_bounds__(512) void k_bucket(const int* __restrict__ src,
                                                const int* __restrict__ dst,
                                                const int* __restrict__ M,
                                                const int* __restrict__ R,
                                                int2* __restrict__ bucket) {
    __shared__ int cur[NR];
    int c = blockIdx.x;
    for (int i = threadIdx.x; i < NR; i += 512) cur[i] = M[c * NR + i] + R[i];
    __syncthreads();
    int e0 = c * CHSZ, e1 = min(e0 + CHSZ, Ee);
    const int4* d4 = reinterpret_cast<const int4*>(dst + e0);
    const int4* s4 = reinterpret_cast<const int4*>(src + e0);
    int n4 = (e1 - e0) >> 2;
    for (int i = threadIdx.x; i < n4; i += 512) {
        int4 d = d4[i];
        int4 s = s4[i];
        int sl;
        sl = atomicAdd(&cur[d.x >> RSH], 1); bucket[sl] = make_int2(s.x, d.x);
        sl = atomicAdd(&cur[d.y >> RSH], 1); bucket[sl] = make_int2(s.y, d.y);
        sl = atomicAdd(&cur[d.z >> RSH], 1); bucket[sl] = make_int2(s.z, d.z);
        sl = atomicAdd(&cur[d.w >> RSH], 1); bucket[sl] = make_int2(s.w, d.w);
    }
}

// ---------- S4: per-range CSR build + deg + dinv + rowptr ----------
__global__ __launch_bounds__(512) void k_build(const int2* __restrict__ bucket,
                                               const int* __restrict__ R,
                                               int* __restrict__ csr,
                                               int* __restrict__ rowptr,
                                               int* __restrict__ deg,
                                               float* __restrict__ dinv) {
    __shared__ int hist[256];
    __shared__ int scn[256];
    __shared__ int cur[256];
    int t = threadIdx.x, r = blockIdx.x;
    int lo = r << RSH;
    int cnt = min(256, Nn - lo);
    int b0 = R[r], b1 = R[r + 1];
    if (t < 256) hist[t] = 0;
    __syncthreads();
    for (int i = b0 + t; i < b1; i += 512) {
        int2 e = bucket[i];
        atomicAdd(&hist[e.y - lo], 1);
    }
    __syncthreads();
    int hv = (t < 256) ? hist[t] : 0;
    if (t < 256) scn[t] = hv;
    __syncthreads();
    for (int off = 1; off < 256; off <<= 1) {
        int x = 0;
        if (t < 256 && t >= off) x = scn[t - off];
        __syncthreads();
        if (t < 256) scn[t] += x;
        __syncthreads();
    }
    if (t < cnt) {
        int base = b0 + (scn[t] - hv);   // exclusive within range + range start
        rowptr[lo + t] = base;
        deg[lo + t] = hv;
        dinv[lo + t] = rsqrtf((float)hv + 1.0f);
        cur[t] = base;
    }
    __syncthreads();
    for (int i = b0 + t; i < b1; i += 512) {
        int2 e = bucket[i];
        int sl = atomicAdd(&cur[e.y - lo], 1);
        csr[sl] = e.x;
    }
}

// ---------- layer-1 GEMM: LDS-tiled, coalesced (K = 128) ----------
// Block = 256 thr: stage 64-row x-tile (32 KB) + W (16 KB) in LDS; each
// thread computes 8 rows x 1 col. Output pre-scaled by dinv[row].
constexpr int TM = 64;
__global__ __launch_bounds__(256) void k_gemm128(const float* __restrict__ x,
                                                 const float* __restrict__ W,
                                                 const float* __restrict__ dinv,
                                                 float* __restrict__ hls) {
    __shared__ float xt[TM * FIN];   // 32 KB
    __shared__ float ws[FIN * Hh];   // 16 KB
    int tid = threadIdx.x;
#pragma unroll
    for (int i = 0; i < (FIN * Hh) / 256; ++i) ws[tid + 256 * i] = W[tid + 256 * i];
    int row0 = blockIdx.x * TM;
    const float4* x4 = reinterpret_cast<const float4*>(x);
    float4* xt4 = reinterpret_cast<float4*>(xt);
#pragma unroll
    for (int j = 0; j < (TM * FIN / 4) / 256; ++j) {   // 8 float4 per thread
        int f = tid + 256 * j;                          // f4 index in tile
        int r = row0 + (f >> 5);                        // FIN/4 = 32 f4 per row
        if (r < Nn) xt4[f] = x4[(size_t)r * 32 + (f & 31)];
    }
    __syncthreads();
    int col = tid & 31;
    int rg  = tid >> 5;       // 8 row-groups of 8 rows
    float acc[8] = {0.f, 0.f, 0.f, 0.f, 0.f, 0.f, 0.f, 0.f};
    const float4* xtf = reinterpret_cast<const float4*>(xt);
    for (int k4 = 0; k4 < FIN / 4; ++k4) {
        float w0 = ws[(4 * k4 + 0) * Hh + col];
        float w1 = ws[(4 * k4 + 1) * Hh + col];
        float w2 = ws[(4 * k4 + 2) * Hh + col];
        float w3 = ws[(4 * k4 + 3) * Hh + col];
#pragma unroll
        for (int i = 0; i < 8; ++i) {
            float4 xv = xtf[(rg * 8 + i) * 32 + k4];
            acc[i] = fmaf(xv.x, w0, acc[i]);
            acc[i] = fmaf(xv.y, w1, acc[i]);
            acc[i] = fmaf(xv.z, w2, acc[i]);
            acc[i] = fmaf(xv.w, w3, acc[i]);
        }
    }
#pragma unroll
    for (int i = 0; i < 8; ++i) {
        int r = row0 + rg * 8 + i;
        if (r < Nn) hls[(size_t)r * Hh + col] = acc[i] * dinv[r];
    }
}

// ---------- fused aggregation + next-layer GEMM ----------
// Gather CSR from hls (pre-scaled), + self loop + bias + relu -> h row, then
// in-register 32x32 GEMM via __shfl (row lives across the 32 lanes), write
// (h @ Wn) * dinv[n]. Eliminates the separate K=32 GEMM kernel + traffic.
__global__ __launch_bounds__(256) void k_aggemm(const float* __restrict__ hls,
                                                const int* __restrict__ csr,
                                                const int* __restrict__ rowptr,
                                                const int* __restrict__ deg,
                                                const float* __restrict__ dinv,
                                                const float* __restrict__ b,
                                                const float* __restrict__ Wn,
                                                float* __restrict__ hout) {
    __shared__ float ws[Hh * Hh];
    int tid = threadIdx.x;
    ws[tid]       = Wn[tid];
    ws[tid + 256] = Wn[tid + 256];
    ws[tid + 512] = Wn[tid + 512];
    ws[tid + 768] = Wn[tid + 768];
    __syncthreads();
    long long t = (long long)blockIdx.x * 256 + tid;
    int n = (int)(t >> 5);
    int col = (int)(t & 31);
    if (n >= Nn) return;
    int beg = rowptr[n];
    int end = beg + deg[n];
    float acc = 0.f;
    for (int i = beg; i < end; i += 8) {
        int   idx[8];
        float msk[8];
#pragma unroll
        for (int j = 0; j < 8; ++j) {
            int k = i + j;
            int c = csr[k];                 // csr padded by 8 -> always in-bounds
            bool m = (k < end);
            idx[j] = m ? c : n;
            msk[j] = m ? 1.f : 0.f;
        }
        float v[8];
#pragma unroll
        for (int j = 0; j < 8; ++j) v[j] = hls[(size_t)idx[j] * Hh + col];
#pragma unroll
        for (int j = 0; j < 8; ++j) acc = fmaf(msk[j], v[j], acc);
    }
    float di = dinv[n];
    float self = hls[(size_t)n * Hh + col];
    float h = fmaxf(fmaf(di, acc + self, b[col]), 0.f);
    // micro-GEMM: out[col] = sum_k h_k * Wn[k][col], h_k held by lane k (mod 32)
    float o = 0.f;
#pragma unroll
    for (int k = 0; k < Hh; ++k) {
        float hk = __shfl(h, k, 32);
        o = fmaf(hk, ws[k * Hh + col], o);
    }
    hout[(size_t)n * Hh + col] = o * di;
}

// ---------- final aggregation (no fused GEMM) ----------
__global__ __launch_bounds__(256) void k_agg(const float* __restrict__ hls,
                                             const int* __restrict__ csr,
                                             const int* __restrict__ rowptr,
                                             const int* __restrict__ deg,
                                             const float* __restrict__ dinv,
                                             const float* __restrict__ b,
                                             float* __restrict__ hout) {
    long long t = (long long)blockIdx.x * 256 + threadIdx.x;
    int n = (int)(t >> 5);
    int col = (int)(t & 31);
    if (n >= Nn) return;
    int beg = rowptr[n];
    int end = beg + deg[n];
    float acc = 0.f;
    for (int i = beg; i < end; i += 8) {
        int   idx[8];
        float msk[8];
#pragma unroll
        for (int j = 0; j < 8; ++j) {
            int k = i + j;
            int c = csr[k];
            bool m = (k < end);
            idx[j] = m ? c : n;
            msk[j] = m ? 1.f : 0.f;
        }
        float v[8];
#pragma unroll
        for (int j = 0; j < 8; ++j) v[j] = hls[(size_t)idx[j] * Hh + col];
#pragma unroll
        for (int j = 0; j < 8; ++j) acc = fmaf(msk[j], v[j], acc);
    }
    float self = hls[(size_t)n * Hh + col];
    float o = fmaf(dinv[n], acc + self, b[col]);
    hout[(size_t)n * Hh + col] = fmaxf(o, 0.f);
}

// ---------- segmented mean-pool (batch is sorted) ----------
constexpr int CH = 256;  // nodes per wave
__global__ __launch_bounds__(256) void k_pool(const float* __restrict__ h,
                                              const int* __restrict__ batch,
                                              float* __restrict__ pooled,
                                              int* __restrict__ cnt) {
    int wid = (blockIdx.x * 256 + threadIdx.x) >> 6;
    int lane = threadIdx.x & 63;
    int col = lane & 31;
    int sub = lane >> 5;
    int n0 = wid * CH;
    if (n0 >= Nn) return;
    int nEnd = min(n0 + CH, Nn);
    float acc = 0.f;
    int gcur = -1, cntLoc = 0;
    for (int n = n0 + sub; n < nEnd; n += 2) {
        int g = batch[n];
        if (g != gcur) {
            if (gcur >= 0) {
                atomAddF(&pooled[gcur * Hh + col], acc);
                if (col == 0) atomicAdd(&cnt[gcur], cntLoc);
            }
            acc = 0.f; cntLoc = 0; gcur = g;
        }
        acc += h[(size_t)n * Hh + col];
        cntLoc++;
    }
    if (gcur >= 0) {
        atomAddF(&pooled[gcur * Hh + col], acc);
        if (col == 0) atomicAdd(&cnt[gcur], cntLoc);
    }
}

// ---------- MLP head + log_softmax ----------
__global__ __launch_bounds__(256) void k_head(const float* __restrict__ pooled,
                                              const int* __restrict__ cnt,
                                              const float* __restrict__ Wf1,
                                              const float* __restrict__ bf1,
                                              const float* __restrict__ Wf2,
                                              const float* __restrict__ bf2,
                                              float* __restrict__ out) {
    __shared__ float w1[Hh * Hh];
    __shared__ float w2[Hh * Cc];
    __shared__ float sb1[Hh];
    __shared__ float sb2[Cc];
    int tid = threadIdx.x;
    w1[tid] = Wf1[tid]; w1[tid + 256] = Wf1[tid + 256];
    w1[tid + 512] = Wf1[tid + 512]; w1[tid + 768] = Wf1[tid + 768];
    for (int i = tid; i < Hh * Cc; i += 256) w2[i] = Wf2[i];
    if (tid < Hh) sb1[tid] = bf1[tid];
    if (tid < Cc) sb2[tid] = bf2[tid];
    __syncthreads();

    int g = tid;
    float inv = 1.0f / fmaxf((float)cnt[g], 1.0f);
    float p[Hh];
#pragma unroll
    for (int c = 0; c < Hh; ++c) p[c] = pooled[g * Hh + c] * inv;
    float h1[Hh];
#pragma unroll
    for (int j = 0; j < Hh; ++j) {
        float acc = sb1[j];
#pragma unroll
        for (int k = 0; k < Hh; ++k) acc = fmaf(p[k], w1[k * Hh + j], acc);
        h1[j] = fmaxf(acc, 0.f);
    }
    float lg[Cc];
#pragma unroll
    for (int j = 0; j < Cc; ++j) {
        float acc = sb2[j];
#pragma unroll
        for (int k = 0; k < Hh; ++k) acc = fmaf(h1[k], w2[k * Cc + j], acc);
        lg[j] = acc;
    }
    float m = lg[0];
#pragma unroll
    for (int j = 1; j < Cc; ++j) m = fmaxf(m, lg[j]);
    float s = 0.f;
#pragma unroll
    for (int j = 0; j < Cc; ++j) s += __expf(lg[j] - m);
    float lse = m + __logf(s);
#pragma unroll
    for (int j = 0; j < Cc; ++j) out[g * Cc + j] = lg[j] - lse;
}

extern "C" void kernel_launch(void* const* d_in, const int* in_sizes, int n_in,
                              void* d_out, int out_size, void* d_ws, size_t ws_size,
                              hipStream_t stream) {
    const float* x    = (const float*)d_in[0];
    const int*   ei   = (const int*)d_in[1];   // [2, E] -> src = ei, dst = ei + E
    const int*   batch= (const int*)d_in[2];
    const float* W1   = (const float*)d_in[3];
    const float* b1   = (const float*)d_in[4];
    const float* W2   = (const float*)d_in[5];
    const float* b2   = (const float*)d_in[6];
    const float* W3   = (const float*)d_in[7];
    const float* b3   = (const float*)d_in[8];
    const float* W4   = (const float*)d_in[9];
    const float* b4   = (const float*)d_in[10];
    const float* Wf1  = (const float*)d_in[11];
    const float* bf1  = (const float*)d_in[12];
    const float* Wf2  = (const float*)d_in[13];
    const float* bf2  = (const float*)d_in[14];
    float* out = (float*)d_out;

    const int* src = ei;
    const int* dst = ei + Ee;

    // Workspace layout. bucket (int2[Ee], 12.8 MB) aliases hl: bucket is dead
    // after k_build, hl is first written by k_gemm128 (strictly after).
    char* ws = (char*)d_ws;
    float* hl     = (float*)ws;   ws += sizeof(float) * Nn * Hh;   // 12.8 MB (= bucket)
    int2*  bucket = (int2*)hl;
    float* hbuf   = (float*)ws;   ws += sizeof(float) * Nn * Hh;   // 12.8 MB
    int*   csr    = (int*)ws;     ws += sizeof(int) * (Ee + 8);    // +8 pad for masked tail
    int*   M      = (int*)ws;     ws += sizeof(int) * NCH * NR;    // 306 KB
    int*   T      = (int*)ws;     ws += sizeof(int) * NR;
    int*   R      = (int*)ws;     ws += sizeof(int) * (NR + 1);
    int*   rowptr = (int*)ws;     ws += sizeof(int) * Nn;
    int*   deg    = (int*)ws;     ws += sizeof(int) * Nn;
    float* dinv   = (float*)ws;   ws += sizeof(float) * Nn;
    float* pooled = (float*)ws;   ws += sizeof(float) * Gg * Hh;
    int*   cnt    = (int*)ws;     ws += sizeof(int) * Gg;

    const int nbNodeCol = (Nn * Hh + 255) / 256;           // 12500
    const int nbTile    = (Nn + TM - 1) / TM;              // 1563

    // ---- graph preprocessing: counting sort -> CSR, deg, dinv, rowptr ----
    k_count <<<NCH, 512, 0, stream>>>(dst, M);
    k_scanM <<<NR, 256, 0, stream>>>(M, T);
    k_scanT <<<1, 512, 0, stream>>>(T, R);
    k_bucket<<<NCH, 512, 0, stream>>>(src, dst, M, R, bucket);
    k_build <<<NR, 512, 0, stream>>>(bucket, R, csr, rowptr, deg, dinv);

    // ---- layer 1 GEMM ----
    k_gemm128<<<nbTile, 256, 0, stream>>>(x, W1, dinv, hl);

    // ---- layers 1..3 aggregation fused with next layer's GEMM ----
    k_aggemm<<<nbNodeCol, 256, 0, stream>>>(hl, csr, rowptr, deg, dinv, b1, W2, hbuf);
    k_aggemm<<<nbNodeCol, 256, 0, stream>>>(hbuf, csr, rowptr, deg, dinv, b2, W3, hl);
    k_aggemm<<<nbNodeCol, 256, 0, stream>>>(hl, csr, rowptr, deg, dinv, b3, W4, hbuf);

    // ---- layer 4 aggregation (final h) ----
    k_agg<<<nbNodeCol, 256, 0, stream>>>(hbuf, csr, rowptr, deg, dinv, b4, hl);

    // ---- pool + head ----
    hipMemsetAsync(pooled, 0, sizeof(float) * Gg * Hh, stream);
    hipMemsetAsync(cnt, 0, sizeof(int) * Gg, stream);
    {
        int waves = (Nn + CH - 1) / CH;
        int blocks = (waves * 64 + 255) / 256;
        k_pool<<<blocks, 256, 0, stream>>>(hl, batch, pooled, cnt);
    }
    k_head<<<1, 256, 0, stream>>>(pooled, cnt, Wf1, bf1, Wf2, bf2, out);
}

// Round 9
// 292.750 us; speedup vs baseline: 4.3207x; 1.0298x over previous
//
#include <hip/hip_runtime.h>
#include <hip/hip_bf16.h>

// Problem constants (fixed by the reference)
constexpr int Nn  = 100000;   // nodes
constexpr int Ee  = 1600000;  // edges
constexpr int FIN = 128;      // input features
constexpr int Hh  = 32;       // hidden
constexpr int Cc  = 10;       // classes
constexpr int Gg  = 256;      // graphs

// Two-level counting sort: ranges of 256 nodes, chunks of 8192 edges.
constexpr int RSH  = 8;                          // range shift (256 nodes)
constexpr int NR   = (Nn + 255) >> RSH;          // 391 ranges
constexpr int CHSZ = 8192;                       // edges per chunk
constexpr int NCH  = (Ee + CHSZ - 1) / CHSZ;     // 196 chunks

__device__ __forceinline__ void atomAddF(float* p, float v) {
    unsafeAtomicAdd(p, v);    // HW global_atomic_add_f32 on gfx950
}

__device__ __forceinline__ float bf2f(__hip_bfloat16 v) { return __bfloat162float(v); }
__device__ __forceinline__ __hip_bfloat16 f2bf(float v) { return __float2bfloat16(v); }

// ---------- S1: per-chunk histogram over node ranges ----------
__global__ __launch_bounds__(512) void k_count(const int* __restrict__ dst,
                                               int* __restrict__ M) {
    __shared__ int hist[NR];
    int c = blockIdx.x;
    for (int i = threadIdx.x; i < NR; i += 512) hist[i] = 0;
    __syncthreads();
    int e0 = c * CHSZ, e1 = min(e0 + CHSZ, Ee);
    const int4* d4 = reinterpret_cast<const int4*>(dst + e0);
    int n4 = (e1 - e0) >> 2;
    for (int i = threadIdx.x; i < n4; i += 512) {
        int4 d = d4[i];
        atomicAdd(&hist[d.x >> RSH], 1);
        atomicAdd(&hist[d.y >> RSH], 1);
        atomicAdd(&hist[d.z >> RSH], 1);
        atomicAdd(&hist[d.w >> RSH], 1);
    }
    __syncthreads();
    for (int i = threadIdx.x; i < NR; i += 512) M[c * NR + i] = hist[i];
}

// ---------- S2a: per-range exclusive scan over chunks (in place), totals -> T
__global__ __launch_bounds__(256) void k_scanM(int* __restrict__ M,
                                               int* __restrict__ T) {
    __shared__ int sh[256];
    int t = threadIdx.x, r = blockIdx.x;
    int v = (t < NCH) ? M[t * NR + r] : 0;
    sh[t] = v;
    __syncthreads();
    for (int off = 1; off < 256; off <<= 1) {
        int x = (t >= off) ? sh[t - off] : 0;
        __syncthreads();
        sh[t] += x;
        __syncthreads();
    }
    if (t < NCH) M[t * NR + r] = sh[t] - v;   // exclusive
    if (t == 255) T[r] = sh[255];
}

// ---------- S2b: exclusive scan of range totals -> R (R[NR] = Ee) ----------
__global__ __launch_bounds__(512) void k_scanT(const int* __restrict__ T,
                                               int* __restrict__ R) {
    __shared__ int sh[512];
    int t = threadIdx.x;
    int v = (t < NR) ? T[t] : 0;
    sh[t] = v;
    __syncthreads();
    for (int off = 1; off < 512; off <<= 1) {
        int x = (t >= off) ? sh[t - off] : 0;
        __syncthreads();
        sh[t] += x;
        __syncthreads();
    }
    if (t < NR) R[t] = sh[t] - v;
    if (t == 511) R[NR] = sh[511];
}

// ---------- S3: scatter (src,dst) into range-grouped bucket ----------
__global__ __launch_bounds__(512) void k_bucket(const int* __restrict__ src,
                                                const int* __restrict__ dst,
                                                const int* __restrict__ M,
                                                const int* __restrict__ R,
                                                int2* __restrict__ bucket) {
    __shared__ int cur[NR];
    int c = blockIdx.x;
    for (int i = threadIdx.x; i < NR; i += 512) cur[i] = M[c * NR + i] + R[i];
    __syncthreads();
    int e0 = c * CHSZ, e1 = min(e0 + CHSZ, Ee);
    const int4* d4 = reinterpret_cast<const int4*>(dst + e0);
    const int4* s4 = reinterpret_cast<const int4*>(src + e0);
    int n4 = (e1 - e0) >> 2;
    for (int i = threadIdx.x; i < n4; i += 512) {
        int4 d = d4[i];
        int4 s = s4[i];
        int sl;
        sl = atomicAdd(&cur[d.x >> RSH], 1); bucket[sl] = make_int2(s.x, d.x);
        sl = atomicAdd(&cur[d.y >> RSH], 1); bucket[sl] = make_int2(s.y, d.y);
        sl = atomicAdd(&cur[d.z >> RSH], 1); bucket[sl] = make_int2(s.z, d.z);
        sl = atomicAdd(&cur[d.w >> RSH], 1); bucket[sl] = make_int2(s.w, d.w);
    }
}

// ---------- S4: per-range CSR build + deg + dinv + rowptr ----------
__global__ __launch_bounds__(512) void k_build(const int2* __restrict__ bucket,
                                               const int* __restrict__ R,
                                               int* __restrict__ csr,
                                               int* __restrict__ rowptr,
                                               int* __restrict__ deg,
                                               float* __restrict__ dinv) {
    __shared__ int hist[256];
    __shared__ int scn[256];
    __shared__ int cur[256];
    int t = threadIdx.x, r = blockIdx.x;
    int lo = r << RSH;
    int cnt = min(256, Nn - lo);
    int b0 = R[r], b1 = R[r + 1];
    if (t < 256) hist[t] = 0;
    __syncthreads();
    for (int i = b0 + t; i < b1; i += 512) {
        int2 e = bucket[i];
        atomicAdd(&hist[e.y - lo], 1);
    }
    __syncthreads();
    int hv = (t < 256) ? hist[t] : 0;
    if (t < 256) scn[t] = hv;
    __syncthreads();
    for (int off = 1; off < 256; off <<= 1) {
        int x = 0;
        if (t < 256 && t >= off) x = scn[t - off];
        __syncthreads();
        if (t < 256) scn[t] += x;
        __syncthreads();
    }
    if (t < cnt) {
        int base = b0 + (scn[t] - hv);   // exclusive within range + range start
        rowptr[lo + t] = base;
        deg[lo + t] = hv;
        dinv[lo + t] = rsqrtf((float)hv + 1.0f);
        cur[t] = base;
    }
    __syncthreads();
    for (int i = b0 + t; i < b1; i += 512) {
        int2 e = bucket[i];
        int sl = atomicAdd(&cur[e.y - lo], 1);
        csr[sl] = e.x;
    }
}

// ---------- layer-1 GEMM: LDS-tiled, coalesced (K = 128), bf16 out ----------
constexpr int TM = 64;
__global__ __launch_bounds__(256) void k_gemm128(const float* __restrict__ x,
                                                 const float* __restrict__ W,
                                                 const float* __restrict__ dinv,
                                                 __hip_bfloat16* __restrict__ hls) {
    __shared__ float xt[TM * FIN];   // 32 KB
    __shared__ float ws[FIN * Hh];   // 16 KB
    int tid = threadIdx.x;
#pragma unroll
    for (int i = 0; i < (FIN * Hh) / 256; ++i) ws[tid + 256 * i] = W[tid + 256 * i];
    int row0 = blockIdx.x * TM;
    const float4* x4 = reinterpret_cast<const float4*>(x);
    float4* xt4 = reinterpret_cast<float4*>(xt);
#pragma unroll
    for (int j = 0; j < (TM * FIN / 4) / 256; ++j) {   // 8 float4 per thread
        int f = tid + 256 * j;                          // f4 index in tile
        int r = row0 + (f >> 5);                        // FIN/4 = 32 f4 per row
        if (r < Nn) xt4[f] = x4[(size_t)r * 32 + (f & 31)];
    }
    __syncthreads();
    int col = tid & 31;
    int rg  = tid >> 5;       // 8 row-groups of 8 rows
    float acc[8] = {0.f, 0.f, 0.f, 0.f, 0.f, 0.f, 0.f, 0.f};
    const float4* xtf = reinterpret_cast<const float4*>(xt);
    for (int k4 = 0; k4 < FIN / 4; ++k4) {
        float w0 = ws[(4 * k4 + 0) * Hh + col];
        float w1 = ws[(4 * k4 + 1) * Hh + col];
        float w2 = ws[(4 * k4 + 2) * Hh + col];
        float w3 = ws[(4 * k4 + 3) * Hh + col];
#pragma unroll
        for (int i = 0; i < 8; ++i) {
            float4 xv = xtf[(rg * 8 + i) * 32 + k4];
            acc[i] = fmaf(xv.x, w0, acc[i]);
            acc[i] = fmaf(xv.y, w1, acc[i]);
            acc[i] = fmaf(xv.z, w2, acc[i]);
            acc[i] = fmaf(xv.w, w3, acc[i]);
        }
    }
#pragma unroll
    for (int i = 0; i < 8; ++i) {
        int r = row0 + rg * 8 + i;
        if (r < Nn) hls[(size_t)r * Hh + col] = f2bf(acc[i] * dinv[r]);
    }
}

// ---------- fused aggregation + next-layer GEMM (bf16 features) ----------
__global__ __launch_bounds__(256) void k_aggemm(const __hip_bfloat16* __restrict__ hls,
                                                const int* __restrict__ csr,
                                                const int* __restrict__ rowptr,
                                                const int* __restrict__ deg,
                                                const float* __restrict__ dinv,
                                                const float* __restrict__ b,
                                                const float* __restrict__ Wn,
                                                __hip_bfloat16* __restrict__ hout) {
    __shared__ float ws[Hh * Hh];
    int tid = threadIdx.x;
    ws[tid]       = Wn[tid];
    ws[tid + 256] = Wn[tid + 256];
    ws[tid + 512] = Wn[tid + 512];
    ws[tid + 768] = Wn[tid + 768];
    __syncthreads();
    long long t = (long long)blockIdx.x * 256 + tid;
    int n = (int)(t >> 5);
    int col = (int)(t & 31);
    if (n >= Nn) return;
    int beg = rowptr[n];
    int end = beg + deg[n];
    float acc = 0.f;
    for (int i = beg; i < end; i += 8) {
        int   idx[8];
        float msk[8];
#pragma unroll
        for (int j = 0; j < 8; ++j) {
            int k = i + j;
            int c = csr[k];                 // csr padded by 8 -> always in-bounds
            bool m = (k < end);
            idx[j] = m ? c : n;
            msk[j] = m ? 1.f : 0.f;
        }
        float v[8];
#pragma unroll
        for (int j = 0; j < 8; ++j) v[j] = bf2f(hls[(size_t)idx[j] * Hh + col]);
#pragma unroll
        for (int j = 0; j < 8; ++j) acc = fmaf(msk[j], v[j], acc);
    }
    float di = dinv[n];
    float self = bf2f(hls[(size_t)n * Hh + col]);
    float h = fmaxf(fmaf(di, acc + self, b[col]), 0.f);
    // micro-GEMM: out[col] = sum_k h_k * Wn[k][col], h_k held by lane k (mod 32)
    float o = 0.f;
#pragma unroll
    for (int k = 0; k < Hh; ++k) {
        float hk = __shfl(h, k, 32);
        o = fmaf(hk, ws[k * Hh + col], o);
    }
    hout[(size_t)n * Hh + col] = f2bf(o * di);
}

// ---------- final aggregation (no fused GEMM), bf16 in/out ----------
__global__ __launch_bounds__(256) void k_agg(const __hip_bfloat16* __restrict__ hls,
                                             const int* __restrict__ csr,
                                             const int* __restrict__ rowptr,
                                             const int* __restrict__ deg,
                                             const float* __restrict__ dinv,
                                             const float* __restrict__ b,
                                             __hip_bfloat16* __restrict__ hout) {
    long long t = (long long)blockIdx.x * 256 + threadIdx.x;
    int n = (int)(t >> 5);
    int col = (int)(t & 31);
    if (n >= Nn) return;
    int beg = rowptr[n];
    int end = beg + deg[n];
    float acc = 0.f;
    for (int i = beg; i < end; i += 8) {
        int   idx[8];
        float msk[8];
#pragma unroll
        for (int j = 0; j < 8; ++j) {
            int k = i + j;
            int c = csr[k];
            bool m = (k < end);
            idx[j] = m ? c : n;
            msk[j] = m ? 1.f : 0.f;
        }
        float v[8];
#pragma unroll
        for (int j = 0; j < 8; ++j) v[j] = bf2f(hls[(size_t)idx[j] * Hh + col]);
#pragma unroll
        for (int j = 0; j < 8; ++j) acc = fmaf(msk[j], v[j], acc);
    }
    float self = bf2f(hls[(size_t)n * Hh + col]);
    float o = fmaf(dinv[n], acc + self, b[col]);
    hout[(size_t)n * Hh + col] = f2bf(fmaxf(o, 0.f));
}

// ---------- segmented mean-pool (batch is sorted), bf16 in ----------
constexpr int CH = 256;  // nodes per wave
__global__ __launch_bounds__(256) void k_pool(const __hip_bfloat16* __restrict__ h,
                                              const int* __restrict__ batch,
                                              float* __restrict__ pooled,
                                              int* __restrict__ cnt) {
    int wid = (blockIdx.x * 256 + threadIdx.x) >> 6;
    int lane = threadIdx.x & 63;
    int col = lane & 31;
    int sub = lane >> 5;
    int n0 = wid * CH;
    if (n0 >= Nn) return;
    int nEnd = min(n0 + CH, Nn);
    float acc = 0.f;
    int gcur = -1, cntLoc = 0;
    for (int n = n0 + sub; n < nEnd; n += 2) {
        int g = batch[n];
        if (g != gcur) {
            if (gcur >= 0) {
                atomAddF(&pooled[gcur * Hh + col], acc);
                if (col == 0) atomicAdd(&cnt[gcur], cntLoc);
            }
            acc = 0.f; cntLoc = 0; gcur = g;
        }
        acc += bf2f(h[(size_t)n * Hh + col]);
        cntLoc++;
    }
    if (gcur >= 0) {
        atomAddF(&pooled[gcur * Hh + col], acc);
        if (col == 0) atomicAdd(&cnt[gcur], cntLoc);
    }
}

// ---------- MLP head + log_softmax ----------
__global__ __launch_bounds__(256) void k_head(const float* __restrict__ pooled,
                                              const int* __restrict__ cnt,
                                              const float* __restrict__ Wf1,
                                              const float* __restrict__ bf1,
                                              const float* __restrict__ Wf2,
                                              const float* __restrict__ bf2,
                                              float* __restrict__ out) {
    __shared__ float w1[Hh * Hh];
    __shared__ float w2[Hh * Cc];
    __shared__ float sb1[Hh];
    __shared__ float sb2[Cc];
    int tid = threadIdx.x;
    w1[tid] = Wf1[tid]; w1[tid + 256] = Wf1[tid + 256];
    w1[tid + 512] = Wf1[tid + 512]; w1[tid + 768] = Wf1[tid + 768];
    for (int i = tid; i < Hh * Cc; i += 256) w2[i] = Wf2[i];
    if (tid < Hh) sb1[tid] = bf1[tid];
    if (tid < Cc) sb2[tid] = bf2[tid];
    __syncthreads();

    int g = tid;
    float inv = 1.0f / fmaxf((float)cnt[g], 1.0f);
    float p[Hh];
#pragma unroll
    for (int c = 0; c < Hh; ++c) p[c] = pooled[g * Hh + c] * inv;
    float h1[Hh];
#pragma unroll
    for (int j = 0; j < Hh; ++j) {
        float acc = sb1[j];
#pragma unroll
        for (int k = 0; k < Hh; ++k) acc = fmaf(p[k], w1[k * Hh + j], acc);
        h1[j] = fmaxf(acc, 0.f);
    }
    float lg[Cc];
#pragma unroll
    for (int j = 0; j < Cc; ++j) {
        float acc = sb2[j];
#pragma unroll
        for (int k = 0; k < Hh; ++k) acc = fmaf(h1[k], w2[k * Cc + j], acc);
        lg[j] = acc;
    }
    float m = lg[0];
#pragma unroll
    for (int j = 1; j < Cc; ++j) m = fmaxf(m, lg[j]);
    float s = 0.f;
#pragma unroll
    for (int j = 0; j < Cc; ++j) s += __expf(lg[j] - m);
    float lse = m + __logf(s);
#pragma unroll
    for (int j = 0; j < Cc; ++j) out[g * Cc + j] = lg[j] - lse;
}

extern "C" void kernel_launch(void* const* d_in, const int* in_sizes, int n_in,
                              void* d_out, int out_size, void* d_ws, size_t ws_size,
                              hipStream_t stream) {
    const float* x    = (const float*)d_in[0];
    const int*   ei   = (const int*)d_in[1];   // [2, E] -> src = ei, dst = ei + E
    const int*   batch= (const int*)d_in[2];
    const float* W1   = (const float*)d_in[3];
    const float* b1   = (const float*)d_in[4];
    const float* W2   = (const float*)d_in[5];
    const float* b2   = (const float*)d_in[6];
    const float* W3   = (const float*)d_in[7];
    const float* b3   = (const float*)d_in[8];
    const float* W4   = (const float*)d_in[9];
    const float* b4   = (const float*)d_in[10];
    const float* Wf1  = (const float*)d_in[11];
    const float* bf1  = (const float*)d_in[12];
    const float* Wf2  = (const float*)d_in[13];
    const float* bf2  = (const float*)d_in[14];
    float* out = (float*)d_out;

    const int* src = ei;
    const int* dst = ei + Ee;

    // Workspace layout (8B-aligned first)
    char* ws = (char*)d_ws;
    int2*  bucket = (int2*)ws;    ws += sizeof(int2) * Ee;                   // 12.8 MB
    __hip_bfloat16* hl   = (__hip_bfloat16*)ws; ws += sizeof(__hip_bfloat16) * Nn * Hh;  // 6.4 MB
    __hip_bfloat16* hbuf = (__hip_bfloat16*)ws; ws += sizeof(__hip_bfloat16) * Nn * Hh;  // 6.4 MB
    int*   csr    = (int*)ws;     ws += sizeof(int) * (Ee + 8);              // +8 pad
    int*   M      = (int*)ws;     ws += sizeof(int) * NCH * NR;              // 306 KB
    int*   T      = (int*)ws;     ws += sizeof(int) * NR;
    int*   R      = (int*)ws;     ws += sizeof(int) * (NR + 1);
    int*   rowptr = (int*)ws;     ws += sizeof(int) * Nn;
    int*   deg    = (int*)ws;     ws += sizeof(int) * Nn;
    float* dinv   = (float*)ws;   ws += sizeof(float) * Nn;
    float* pooled = (float*)ws;   ws += sizeof(float) * Gg * Hh;
    int*   cnt    = (int*)ws;     ws += sizeof(int) * Gg;

    const int nbNodeCol = (Nn * Hh + 255) / 256;           // 12500
    const int nbTile    = (Nn + TM - 1) / TM;              // 1563

    // ---- graph preprocessing: counting sort -> CSR, deg, dinv, rowptr ----
    k_count <<<NCH, 512, 0, stream>>>(dst, M);
    k_scanM <<<NR, 256, 0, stream>>>(M, T);
    k_scanT <<<1, 512, 0, stream>>>(T, R);
    k_bucket<<<NCH, 512, 0, stream>>>(src, dst, M, R, bucket);
    k_build <<<NR, 512, 0, stream>>>(bucket, R, csr, rowptr, deg, dinv);

    // ---- layer 1 GEMM ----
    k_gemm128<<<nbTile, 256, 0, stream>>>(x, W1, dinv, hl);

    // ---- layers 1..3 aggregation fused with next layer's GEMM ----
    k_aggemm<<<nbNodeCol, 256, 0, stream>>>(hl, csr, rowptr, deg, dinv, b1, W2, hbuf);
    k_aggemm<<<nbNodeCol, 256, 0, stream>>>(hbuf, csr, rowptr, deg, dinv, b2, W3, hl);
    k_aggemm<<<nbNodeCol, 256, 0, stream>>>(hl, csr, rowptr, deg, dinv, b3, W4, hbuf);

    // ---- layer 4 aggregation (final h) ----
    k_agg<<<nbNodeCol, 256, 0, stream>>>(hbuf, csr, rowptr, deg, dinv, b4, hl);

    // ---- pool + head ----
    hipMemsetAsync(pooled, 0, sizeof(float) * Gg * Hh, stream);
    hipMemsetAsync(cnt, 0, sizeof(int) * Gg, stream);
    {
        int waves = (Nn + CH - 1) / CH;
        int blocks = (waves * 64 + 255) / 256;
        k_pool<<<blocks, 256, 0, stream>>>(hl, batch, pooled, cnt);
    }
    k_head<<<1, 256, 0, stream>>>(pooled, cnt, Wf1, bf1, Wf2, bf2, out);
}

// Round 10
// 265.157 us; speedup vs baseline: 4.7703x; 1.1041x over previous
//
#include <hip/hip_runtime.h>
#include <hip/hip_bf16.h>

// Problem constants (fixed by the reference)
constexpr int Nn  = 100000;   // nodes
constexpr int Ee  = 1600000;  // edges
constexpr int FIN = 128;      // input features
constexpr int Hh  = 32;       // hidden
constexpr int Cc  = 10;       // classes
constexpr int Gg  = 256;      // graphs

// Two-level counting sort: ranges of 256 nodes, chunks of 8192 edges.
constexpr int RSH  = 8;                          // range shift (256 nodes)
constexpr int NR   = (Nn + 255) >> RSH;          // 391 ranges
constexpr int CHSZ = 8192;                       // edges per chunk
constexpr int NCH  = (Ee + CHSZ - 1) / CHSZ;     // 196 chunks

__device__ __forceinline__ void atomAddF(float* p, float v) {
    unsafeAtomicAdd(p, v);    // HW global_atomic_add_f32 on gfx950
}

__device__ __forceinline__ float bf2f(__hip_bfloat16 v) { return __bfloat162float(v); }
__device__ __forceinline__ __hip_bfloat16 f2bf(float v) { return __float2bfloat16(v); }

// ---------- S1: per-chunk histogram over node ranges ----------
__global__ __launch_bounds__(512) void k_count(const int* __restrict__ dst,
                                               int* __restrict__ M) {
    __shared__ int hist[NR];
    int c = blockIdx.x;
    for (int i = threadIdx.x; i < NR; i += 512) hist[i] = 0;
    __syncthreads();
    int e0 = c * CHSZ, e1 = min(e0 + CHSZ, Ee);
    const int4* d4 = reinterpret_cast<const int4*>(dst + e0);
    int n4 = (e1 - e0) >> 2;
    for (int i = threadIdx.x; i < n4; i += 512) {
        int4 d = d4[i];
        atomicAdd(&hist[d.x >> RSH], 1);
        atomicAdd(&hist[d.y >> RSH], 1);
        atomicAdd(&hist[d.z >> RSH], 1);
        atomicAdd(&hist[d.w >> RSH], 1);
    }
    __syncthreads();
    for (int i = threadIdx.x; i < NR; i += 512) M[c * NR + i] = hist[i];
}

// ---------- S2a: per-range exclusive scan over chunks (in place), totals -> T
__global__ __launch_bounds__(256) void k_scanM(int* __restrict__ M,
                                               int* __restrict__ T) {
    __shared__ int sh[256];
    int t = threadIdx.x, r = blockIdx.x;
    int v = (t < NCH) ? M[t * NR + r] : 0;
    sh[t] = v;
    __syncthreads();
    for (int off = 1; off < 256; off <<= 1) {
        int x = (t >= off) ? sh[t - off] : 0;
        __syncthreads();
        sh[t] += x;
        __syncthreads();
    }
    if (t < NCH) M[t * NR + r] = sh[t] - v;   // exclusive
    if (t == 255) T[r] = sh[255];
}

// ---------- S2b: exclusive scan of range totals -> R (R[NR] = Ee) ----------
__global__ __launch_bounds__(512) void k_scanT(const int* __restrict__ T,
                                               int* __restrict__ R) {
    __shared__ int sh[512];
    int t = threadIdx.x;
    int v = (t < NR) ? T[t] : 0;
    sh[t] = v;
    __syncthreads();
    for (int off = 1; off < 512; off <<= 1) {
        int x = (t >= off) ? sh[t - off] : 0;
        __syncthreads();
        sh[t] += x;
        __syncthreads();
    }
    if (t < NR) R[t] = sh[t] - v;
    if (t == 511) R[NR] = sh[511];
}

// ---------- S3: scatter (src,dst) into range-grouped bucket ----------
__global__ __launch_bounds__(512) void k_bucket(const int* __restrict__ src,
                                                const int* __restrict__ dst,
                                                const int* __restrict__ M,
                                                const int* __restrict__ R,
                                                int2* __restrict__ bucket) {
    __shared__ int cur[NR];
    int c = blockIdx.x;
    for (int i = threadIdx.x; i < NR; i += 512) cur[i] = M[c * NR + i] + R[i];
    __syncthreads();
    int e0 = c * CHSZ, e1 = min(e0 + CHSZ, Ee);
    const int4* d4 = reinterpret_cast<const int4*>(dst + e0);
    const int4* s4 = reinterpret_cast<const int4*>(src + e0);
    int n4 = (e1 - e0) >> 2;
    for (int i = threadIdx.x; i < n4; i += 512) {
        int4 d = d4[i];
        int4 s = s4[i];
        int sl;
        sl = atomicAdd(&cur[d.x >> RSH], 1); bucket[sl] = make_int2(s.x, d.x);
        sl = atomicAdd(&cur[d.y >> RSH], 1); bucket[sl] = make_int2(s.y, d.y);
        sl = atomicAdd(&cur[d.z >> RSH], 1); bucket[sl] = make_int2(s.z, d.z);
        sl = atomicAdd(&cur[d.w >> RSH], 1); bucket[sl] = make_int2(s.w, d.w);
    }
}

// ---------- S4: per-range CSR build + deg + dinv + rowptr ----------
__global__ __launch_bounds__(512) void k_build(const int2* __restrict__ bucket,
                                               const int* __restrict__ R,
                                               int* __restrict__ csr,
                                               int* __restrict__ rowptr,
                                               int* __restrict__ deg,
                                               float* __restrict__ dinv) {
    __shared__ int hist[256];
    __shared__ int scn[256];
    __shared__ int cur[256];
    int t = threadIdx.x, r = blockIdx.x;
    int lo = r << RSH;
    int cnt = min(256, Nn - lo);
    int b0 = R[r], b1 = R[r + 1];
    if (t < 256) hist[t] = 0;
    __syncthreads();
    for (int i = b0 + t; i < b1; i += 512) {
        int2 e = bucket[i];
        atomicAdd(&hist[e.y - lo], 1);
    }
    __syncthreads();
    int hv = (t < 256) ? hist[t] : 0;
    if (t < 256) scn[t] = hv;
    __syncthreads();
    for (int off = 1; off < 256; off <<= 1) {
        int x = 0;
        if (t < 256 && t >= off) x = scn[t - off];
        __syncthreads();
        if (t < 256) scn[t] += x;
        __syncthreads();
    }
    if (t < cnt) {
        int base = b0 + (scn[t] - hv);   // exclusive within range + range start
        rowptr[lo + t] = base;
        deg[lo + t] = hv;
        dinv[lo + t] = rsqrtf((float)hv + 1.0f);
        cur[t] = base;
    }
    __syncthreads();
    for (int i = b0 + t; i < b1; i += 512) {
        int2 e = bucket[i];
        int sl = atomicAdd(&cur[e.y - lo], 1);
        csr[sl] = e.x;
    }
}

// ---------- layer-1 GEMM: LDS-tiled, coalesced (K = 128), bf16 out ----------
constexpr int TM = 64;
__global__ __launch_bounds__(256) void k_gemm128(const float* __restrict__ x,
                                                 const float* __restrict__ W,
                                                 const float* __restrict__ dinv,
                                                 __hip_bfloat16* __restrict__ hls) {
    __shared__ float xt[TM * FIN];   // 32 KB
    __shared__ float ws[FIN * Hh];   // 16 KB
    int tid = threadIdx.x;
#pragma unroll
    for (int i = 0; i < (FIN * Hh) / 256; ++i) ws[tid + 256 * i] = W[tid + 256 * i];
    int row0 = blockIdx.x * TM;
    const float4* x4 = reinterpret_cast<const float4*>(x);
    float4* xt4 = reinterpret_cast<float4*>(xt);
#pragma unroll
    for (int j = 0; j < (TM * FIN / 4) / 256; ++j) {   // 8 float4 per thread
        int f = tid + 256 * j;                          // f4 index in tile
        int r = row0 + (f >> 5);                        // FIN/4 = 32 f4 per row
        if (r < Nn) xt4[f] = x4[(size_t)r * 32 + (f & 31)];
    }
    __syncthreads();
    int col = tid & 31;
    int rg  = tid >> 5;       // 8 row-groups of 8 rows
    float acc[8] = {0.f, 0.f, 0.f, 0.f, 0.f, 0.f, 0.f, 0.f};
    const float4* xtf = reinterpret_cast<const float4*>(xt);
    for (int k4 = 0; k4 < FIN / 4; ++k4) {
        float w0 = ws[(4 * k4 + 0) * Hh + col];
        float w1 = ws[(4 * k4 + 1) * Hh + col];
        float w2 = ws[(4 * k4 + 2) * Hh + col];
        float w3 = ws[(4 * k4 + 3) * Hh + col];
#pragma unroll
        for (int i = 0; i < 8; ++i) {
            float4 xv = xtf[(rg * 8 + i) * 32 + k4];
            acc[i] = fmaf(xv.x, w0, acc[i]);
            acc[i] = fmaf(xv.y, w1, acc[i]);
            acc[i] = fmaf(xv.z, w2, acc[i]);
            acc[i] = fmaf(xv.w, w3, acc[i]);
        }
    }
#pragma unroll
    for (int i = 0; i < 8; ++i) {
        int r = row0 + rg * 8 + i;
        if (r < Nn) hls[(size_t)r * Hh + col] = f2bf(acc[i] * dinv[r]);
    }
}

// ---------- fused aggregation + next-layer GEMM (bf16 features) ----------
__global__ __launch_bounds__(256) void k_aggemm(const __hip_bfloat16* __restrict__ hls,
                                                const int* __restrict__ csr,
                                                const int* __restrict__ rowptr,
                                                const int* __restrict__ deg,
                                                const float* __restrict__ dinv,
                                                const float* __restrict__ b,
                                                const float* __restrict__ Wn,
                                                __hip_bfloat16* __restrict__ hout) {
    __shared__ float ws[Hh * Hh];
    int tid = threadIdx.x;
    ws[tid]       = Wn[tid];
    ws[tid + 256] = Wn[tid + 256];
    ws[tid + 512] = Wn[tid + 512];
    ws[tid + 768] = Wn[tid + 768];
    __syncthreads();
    long long t = (long long)blockIdx.x * 256 + tid;
    int n = (int)(t >> 5);
    int col = (int)(t & 31);
    if (n >= Nn) return;
    int beg = rowptr[n];
    int end = beg + deg[n];
    float acc = 0.f;
    for (int i = beg; i < end; i += 8) {
        int   idx[8];
        float msk[8];
#pragma unroll
        for (int j = 0; j < 8; ++j) {
            int k = i + j;
            int c = csr[k];                 // csr padded by 8 -> always in-bounds
            bool m = (k < end);
            idx[j] = m ? c : n;
            msk[j] = m ? 1.f : 0.f;
        }
        float v[8];
#pragma unroll
        for (int j = 0; j < 8; ++j) v[j] = bf2f(hls[(size_t)idx[j] * Hh + col]);
#pragma unroll
        for (int j = 0; j < 8; ++j) acc = fmaf(msk[j], v[j], acc);
    }
    float di = dinv[n];
    float self = bf2f(hls[(size_t)n * Hh + col]);
    float h = fmaxf(fmaf(di, acc + self, b[col]), 0.f);
    // micro-GEMM: out[col] = sum_k h_k * Wn[k][col], h_k held by lane k (mod 32)
    float o = 0.f;
#pragma unroll
    for (int k = 0; k < Hh; ++k) {
        float hk = __shfl(h, k, 32);
        o = fmaf(hk, ws[k * Hh + col], o);
    }
    hout[(size_t)n * Hh + col] = f2bf(o * di);
}

// ---------- final aggregation (no fused GEMM), bf16 in/out ----------
__global__ __launch_bounds__(256) void k_agg(const __hip_bfloat16* __restrict__ hls,
                                             const int* __restrict__ csr,
                                             const int* __restrict__ rowptr,
                                             const int* __restrict__ deg,
                                             const float* __restrict__ dinv,
                                             const float* __restrict__ b,
                                             __hip_bfloat16* __restrict__ hout) {
    long long t = (long long)blockIdx.x * 256 + threadIdx.x;
    int n = (int)(t >> 5);
    int col = (int)(t & 31);
    if (n >= Nn) return;
    int beg = rowptr[n];
    int end = beg + deg[n];
    float acc = 0.f;
    for (int i = beg; i < end; i += 8) {
        int   idx[8];
        float msk[8];
#pragma unroll
        for (int j = 0; j < 8; ++j) {
            int k = i + j;
            int c = csr[k];
            bool m = (k < end);
            idx[j] = m ? c : n;
            msk[j] = m ? 1.f : 0.f;
        }
        float v[8];
#pragma unroll
        for (int j = 0; j < 8; ++j) v[j] = bf2f(hls[(size_t)idx[j] * Hh + col]);
#pragma unroll
        for (int j = 0; j < 8; ++j) acc = fmaf(msk[j], v[j], acc);
    }
    float self = bf2f(hls[(size_t)n * Hh + col]);
    float o = fmaf(dinv[n], acc + self, b[col]);
    hout[(size_t)n * Hh + col] = f2bf(fmaxf(o, 0.f));
}

// ---------- segmented mean-pool (batch is sorted), bf16 in ----------
// CH=16 nodes per wave -> 6250 waves = 1563 blocks (vs 98 at CH=256): the
// round-9 profile showed 3% occupancy / 53 us. Per-wave: lane = (sub, col),
// sub = node parity; running per-graph sums flush on graph change only.
constexpr int CH = 16;  // nodes per wave
__global__ __launch_bounds__(256) void k_pool(const __hip_bfloat16* __restrict__ h,
                                              const int* __restrict__ batch,
                                              float* __restrict__ pooled,
                                              int* __restrict__ cnt) {
    int wid = (blockIdx.x * 256 + threadIdx.x) >> 6;
    int lane = threadIdx.x & 63;
    int col = lane & 31;
    int sub = lane >> 5;
    int n0 = wid * CH;
    if (n0 >= Nn) return;
    int nEnd = min(n0 + CH, Nn);
    float acc = 0.f;
    int gcur = -1, cntLoc = 0;
    for (int n = n0 + sub; n < nEnd; n += 2) {
        int g = batch[n];
        if (g != gcur) {
            if (gcur >= 0) {
                atomAddF(&pooled[gcur * Hh + col], acc);
                if (col == 0) atomicAdd(&cnt[gcur], cntLoc);
            }
            acc = 0.f; cntLoc = 0; gcur = g;
        }
        acc += bf2f(h[(size_t)n * Hh + col]);
        cntLoc++;
    }
    if (gcur >= 0) {
        atomAddF(&pooled[gcur * Hh + col], acc);
        if (col == 0) atomicAdd(&cnt[gcur], cntLoc);
    }
}

// ---------- MLP head + log_softmax ----------
__global__ __launch_bounds__(256) void k_head(const float* __restrict__ pooled,
                                              const int* __restrict__ cnt,
                                              const float* __restrict__ Wf1,
                                              const float* __restrict__ bf1,
                                              const float* __restrict__ Wf2,
                                              const float* __restrict__ bf2,
                                              float* __restrict__ out) {
    __shared__ float w1[Hh * Hh];
    __shared__ float w2[Hh * Cc];
    __shared__ float sb1[Hh];
    __shared__ float sb2[Cc];
    int tid = threadIdx.x;
    w1[tid] = Wf1[tid]; w1[tid + 256] = Wf1[tid + 256];
    w1[tid + 512] = Wf1[tid + 512]; w1[tid + 768] = Wf1[tid + 768];
    for (int i = tid; i < Hh * Cc; i += 256) w2[i] = Wf2[i];
    if (tid < Hh) sb1[tid] = bf1[tid];
    if (tid < Cc) sb2[tid] = bf2[tid];
    __syncthreads();

    int g = tid;
    float inv = 1.0f / fmaxf((float)cnt[g], 1.0f);
    float p[Hh];
#pragma unroll
    for (int c = 0; c < Hh; ++c) p[c] = pooled[g * Hh + c] * inv;
    float h1[Hh];
#pragma unroll
    for (int j = 0; j < Hh; ++j) {
        float acc = sb1[j];
#pragma unroll
        for (int k = 0; k < Hh; ++k) acc = fmaf(p[k], w1[k * Hh + j], acc);
        h1[j] = fmaxf(acc, 0.f);
    }
    float lg[Cc];
#pragma unroll
    for (int j = 0; j < Cc; ++j) {
        float acc = sb2[j];
#pragma unroll
        for (int k = 0; k < Hh; ++k) acc = fmaf(h1[k], w2[k * Cc + j], acc);
        lg[j] = acc;
    }
    float m = lg[0];
#pragma unroll
    for (int j = 1; j < Cc; ++j) m = fmaxf(m, lg[j]);
    float s = 0.f;
#pragma unroll
    for (int j = 0; j < Cc; ++j) s += __expf(lg[j] - m);
    float lse = m + __logf(s);
#pragma unroll
    for (int j = 0; j < Cc; ++j) out[g * Cc + j] = lg[j] - lse;
}

extern "C" void kernel_launch(void* const* d_in, const int* in_sizes, int n_in,
                              void* d_out, int out_size, void* d_ws, size_t ws_size,
                              hipStream_t stream) {
    const float* x    = (const float*)d_in[0];
    const int*   ei   = (const int*)d_in[1];   // [2, E] -> src = ei, dst = ei + E
    const int*   batch= (const int*)d_in[2];
    const float* W1   = (const float*)d_in[3];
    const float* b1   = (const float*)d_in[4];
    const float* W2   = (const float*)d_in[5];
    const float* b2   = (const float*)d_in[6];
    const float* W3   = (const float*)d_in[7];
    const float* b3   = (const float*)d_in[8];
    const float* W4   = (const float*)d_in[9];
    const float* b4   = (const float*)d_in[10];
    const float* Wf1  = (const float*)d_in[11];
    const float* bf1  = (const float*)d_in[12];
    const float* Wf2  = (const float*)d_in[13];
    const float* bf2  = (const float*)d_in[14];
    float* out = (float*)d_out;

    const int* src = ei;
    const int* dst = ei + Ee;

    // Workspace layout (8B-aligned first)
    char* ws = (char*)d_ws;
    int2*  bucket = (int2*)ws;    ws += sizeof(int2) * Ee;                   // 12.8 MB
    __hip_bfloat16* hl   = (__hip_bfloat16*)ws; ws += sizeof(__hip_bfloat16) * Nn * Hh;  // 6.4 MB
    __hip_bfloat16* hbuf = (__hip_bfloat16*)ws; ws += sizeof(__hip_bfloat16) * Nn * Hh;  // 6.4 MB
    int*   csr    = (int*)ws;     ws += sizeof(int) * (Ee + 8);              // +8 pad
    int*   M      = (int*)ws;     ws += sizeof(int) * NCH * NR;              // 306 KB
    int*   T      = (int*)ws;     ws += sizeof(int) * NR;
    int*   R      = (int*)ws;     ws += sizeof(int) * (NR + 1);
    int*   rowptr = (int*)ws;     ws += sizeof(int) * Nn;
    int*   deg    = (int*)ws;     ws += sizeof(int) * Nn;
    float* dinv   = (float*)ws;   ws += sizeof(float) * Nn;
    float* pooled = (float*)ws;   ws += sizeof(float) * Gg * Hh;
    int*   cnt    = (int*)ws;     ws += sizeof(int) * Gg;

    const int nbNodeCol = (Nn * Hh + 255) / 256;           // 12500
    const int nbTile    = (Nn + TM - 1) / TM;              // 1563

    // ---- graph preprocessing: counting sort -> CSR, deg, dinv, rowptr ----
    k_count <<<NCH, 512, 0, stream>>>(dst, M);
    k_scanM <<<NR, 256, 0, stream>>>(M, T);
    k_scanT <<<1, 512, 0, stream>>>(T, R);
    k_bucket<<<NCH, 512, 0, stream>>>(src, dst, M, R, bucket);
    k_build <<<NR, 512, 0, stream>>>(bucket, R, csr, rowptr, deg, dinv);

    // ---- layer 1 GEMM ----
    k_gemm128<<<nbTile, 256, 0, stream>>>(x, W1, dinv, hl);

    // ---- layers 1..3 aggregation fused with next layer's GEMM ----
    k_aggemm<<<nbNodeCol, 256, 0, stream>>>(hl, csr, rowptr, deg, dinv, b1, W2, hbuf);
    k_aggemm<<<nbNodeCol, 256, 0, stream>>>(hbuf, csr, rowptr, deg, dinv, b2, W3, hl);
    k_aggemm<<<nbNodeCol, 256, 0, stream>>>(hl, csr, rowptr, deg, dinv, b3, W4, hbuf);

    // ---- layer 4 aggregation (final h) ----
    k_agg<<<nbNodeCol, 256, 0, stream>>>(hbuf, csr, rowptr, deg, dinv, b4, hl);

    // ---- pool + head ----
    hipMemsetAsync(pooled, 0, sizeof(float) * Gg * Hh, stream);
    hipMemsetAsync(cnt, 0, sizeof(int) * Gg, stream);
    {
        int waves = (Nn + CH - 1) / CH;               // 6250
        int blocks = (waves * 64 + 255) / 256;        // 1563
        k_pool<<<blocks, 256, 0, stream>>>(hl, batch, pooled, cnt);
    }
    k_head<<<1, 256, 0, stream>>>(pooled, cnt, Wf1, bf1, Wf2, bf2, out);
}

// Round 11
// 227.127 us; speedup vs baseline: 5.5691x; 1.1674x over previous
//
#include <hip/hip_runtime.h>
#include <hip/hip_bf16.h>

// Problem constants (fixed by the reference)
constexpr int Nn  = 100000;   // nodes
constexpr int Ee  = 1600000;  // edges
constexpr int FIN = 128;      // input features
constexpr int Hh  = 32;       // hidden
constexpr int Cc  = 10;       // classes
constexpr int Gg  = 256;      // graphs

// Two-level counting sort: ranges of 256 nodes, chunks of 8192 edges.
constexpr int RSH  = 8;                          // range shift (256 nodes)
constexpr int NR   = (Nn + 255) >> RSH;          // 391 ranges
constexpr int CHSZ = 8192;                       // edges per chunk
constexpr int NCH  = (Ee + CHSZ - 1) / CHSZ;     // 196 chunks

__device__ __forceinline__ void atomAddF(float* p, float v) {
    unsafeAtomicAdd(p, v);    // HW global_atomic_add_f32 on gfx950
}

__device__ __forceinline__ float bf2f(__hip_bfloat16 v) { return __bfloat162float(v); }
__device__ __forceinline__ __hip_bfloat16 f2bf(float v) { return __float2bfloat16(v); }

// ---------- S1: per-chunk histogram over node ranges ----------
__global__ __launch_bounds__(512) void k_count(const int* __restrict__ dst,
                                               int* __restrict__ M) {
    __shared__ int hist[NR];
    int c = blockIdx.x;
    for (int i = threadIdx.x; i < NR; i += 512) hist[i] = 0;
    __syncthreads();
    int e0 = c * CHSZ, e1 = min(e0 + CHSZ, Ee);
    const int4* d4 = reinterpret_cast<const int4*>(dst + e0);
    int n4 = (e1 - e0) >> 2;
    for (int i = threadIdx.x; i < n4; i += 512) {
        int4 d = d4[i];
        atomicAdd(&hist[d.x >> RSH], 1);
        atomicAdd(&hist[d.y >> RSH], 1);
        atomicAdd(&hist[d.z >> RSH], 1);
        atomicAdd(&hist[d.w >> RSH], 1);
    }
    __syncthreads();
    for (int i = threadIdx.x; i < NR; i += 512) M[c * NR + i] = hist[i];
}

// ---------- S2a: per-range exclusive scan over chunks (in place), totals -> T
__global__ __launch_bounds__(256) void k_scanM(int* __restrict__ M,
                                               int* __restrict__ T) {
    __shared__ int sh[256];
    int t = threadIdx.x, r = blockIdx.x;
    int v = (t < NCH) ? M[t * NR + r] : 0;
    sh[t] = v;
    __syncthreads();
    for (int off = 1; off < 256; off <<= 1) {
        int x = (t >= off) ? sh[t - off] : 0;
        __syncthreads();
        sh[t] += x;
        __syncthreads();
    }
    if (t < NCH) M[t * NR + r] = sh[t] - v;   // exclusive
    if (t == 255) T[r] = sh[255];
}

// ---------- S2b: exclusive scan of range totals -> R (R[NR] = Ee) ----------
__global__ __launch_bounds__(512) void k_scanT(const int* __restrict__ T,
                                               int* __restrict__ R) {
    __shared__ int sh[512];
    int t = threadIdx.x;
    int v = (t < NR) ? T[t] : 0;
    sh[t] = v;
    __syncthreads();
    for (int off = 1; off < 512; off <<= 1) {
        int x = (t >= off) ? sh[t - off] : 0;
        __syncthreads();
        sh[t] += x;
        __syncthreads();
    }
    if (t < NR) R[t] = sh[t] - v;
    if (t == 511) R[NR] = sh[511];
}

// ---------- S3: scatter (src,dst) into range-grouped bucket ----------
__global__ __launch_bounds__(512) void k_bucket(const int* __restrict__ src,
                                                const int* __restrict__ dst,
                                                const int* __restrict__ M,
                                                const int* __restrict__ R,
                                                int2* __restrict__ bucket) {
    __shared__ int cur[NR];
    int c = blockIdx.x;
    for (int i = threadIdx.x; i < NR; i += 512) cur[i] = M[c * NR + i] + R[i];
    __syncthreads();
    int e0 = c * CHSZ, e1 = min(e0 + CHSZ, Ee);
    const int4* d4 = reinterpret_cast<const int4*>(dst + e0);
    const int4* s4 = reinterpret_cast<const int4*>(src + e0);
    int n4 = (e1 - e0) >> 2;
    for (int i = threadIdx.x; i < n4; i += 512) {
        int4 d = d4[i];
        int4 s = s4[i];
        int sl;
        sl = atomicAdd(&cur[d.x >> RSH], 1); bucket[sl] = make_int2(s.x, d.x);
        sl = atomicAdd(&cur[d.y >> RSH], 1); bucket[sl] = make_int2(s.y, d.y);
        sl = atomicAdd(&cur[d.z >> RSH], 1); bucket[sl] = make_int2(s.z, d.z);
        sl = atomicAdd(&cur[d.w >> RSH], 1); bucket[sl] = make_int2(s.w, d.w);
    }
}

// ---------- S4: per-range CSR build + deg + dinv + rowptr ----------
__global__ __launch_bounds__(512) void k_build(const int2* __restrict__ bucket,
                                               const int* __restrict__ R,
                                               int* __restrict__ csr,
                                               int* __restrict__ rowptr,
                                               int* __restrict__ deg,
                                               float* __restrict__ dinv) {
    __shared__ int hist[256];
    __shared__ int scn[256];
    __shared__ int cur[256];
    int t = threadIdx.x, r = blockIdx.x;
    int lo = r << RSH;
    int cnt = min(256, Nn - lo);
    int b0 = R[r], b1 = R[r + 1];
    if (t < 256) hist[t] = 0;
    __syncthreads();
    for (int i = b0 + t; i < b1; i += 512) {
        int2 e = bucket[i];
        atomicAdd(&hist[e.y - lo], 1);
    }
    __syncthreads();
    int hv = (t < 256) ? hist[t] : 0;
    if (t < 256) scn[t] = hv;
    __syncthreads();
    for (int off = 1; off < 256; off <<= 1) {
        int x = 0;
        if (t < 256 && t >= off) x = scn[t - off];
        __syncthreads();
        if (t < 256) scn[t] += x;
        __syncthreads();
    }
    if (t < cnt) {
        int base = b0 + (scn[t] - hv);   // exclusive within range + range start
        rowptr[lo + t] = base;
        deg[lo + t] = hv;
        dinv[lo + t] = rsqrtf((float)hv + 1.0f);
        cur[t] = base;
    }
    __syncthreads();
    for (int i = b0 + t; i < b1; i += 512) {
        int2 e = bucket[i];
        int sl = atomicAdd(&cur[e.y - lo], 1);
        csr[sl] = e.x;
    }
}

// ---------- layer-1 GEMM: LDS-tiled, coalesced (K = 128), bf16 out ----------
constexpr int TM = 64;
__global__ __launch_bounds__(256) void k_gemm128(const float* __restrict__ x,
                                                 const float* __restrict__ W,
                                                 const float* __restrict__ dinv,
                                                 __hip_bfloat16* __restrict__ hls) {
    __shared__ float xt[TM * FIN];   // 32 KB
    __shared__ float ws[FIN * Hh];   // 16 KB
    int tid = threadIdx.x;
#pragma unroll
    for (int i = 0; i < (FIN * Hh) / 256; ++i) ws[tid + 256 * i] = W[tid + 256 * i];
    int row0 = blockIdx.x * TM;
    const float4* x4 = reinterpret_cast<const float4*>(x);
    float4* xt4 = reinterpret_cast<float4*>(xt);
#pragma unroll
    for (int j = 0; j < (TM * FIN / 4) / 256; ++j) {   // 8 float4 per thread
        int f = tid + 256 * j;                          // f4 index in tile
        int r = row0 + (f >> 5);                        // FIN/4 = 32 f4 per row
        if (r < Nn) xt4[f] = x4[(size_t)r * 32 + (f & 31)];
    }
    __syncthreads();
    int col = tid & 31;
    int rg  = tid >> 5;       // 8 row-groups of 8 rows
    float acc[8] = {0.f, 0.f, 0.f, 0.f, 0.f, 0.f, 0.f, 0.f};
    const float4* xtf = reinterpret_cast<const float4*>(xt);
    for (int k4 = 0; k4 < FIN / 4; ++k4) {
        float w0 = ws[(4 * k4 + 0) * Hh + col];
        float w1 = ws[(4 * k4 + 1) * Hh + col];
        float w2 = ws[(4 * k4 + 2) * Hh + col];
        float w3 = ws[(4 * k4 + 3) * Hh + col];
#pragma unroll
        for (int i = 0; i < 8; ++i) {
            float4 xv = xtf[(rg * 8 + i) * 32 + k4];
            acc[i] = fmaf(xv.x, w0, acc[i]);
            acc[i] = fmaf(xv.y, w1, acc[i]);
            acc[i] = fmaf(xv.z, w2, acc[i]);
            acc[i] = fmaf(xv.w, w3, acc[i]);
        }
    }
#pragma unroll
    for (int i = 0; i < 8; ++i) {
        int r = row0 + rg * 8 + i;
        if (r < Nn) hls[(size_t)r * Hh + col] = f2bf(acc[i] * dinv[r]);
    }
}

// ---------- fused aggregation + next-layer GEMM ----------
// 16 lanes per node, each lane owns cols (2l, 2l+1) as one packed bf16x2
// dword. Gathers are dword loads (half the instructions of the 32-lane
// scheme); unpack = 2 bit-ops; micro-GEMM does 2 outputs per lane with 16
// shfls (width 16). Same bytes on the wire, ~half the dynamic instructions.
__global__ __launch_bounds__(256) void k_aggemm(const __hip_bfloat16* __restrict__ hls,
                                                const int* __restrict__ csr,
                                                const int* __restrict__ rowptr,
                                                const int* __restrict__ deg,
                                                const float* __restrict__ dinv,
                                                const float* __restrict__ b,
                                                const float* __restrict__ Wn,
                                                __hip_bfloat16* __restrict__ hout) {
    __shared__ float ws[Hh * Hh];
    int tid = threadIdx.x;
    ws[tid]       = Wn[tid];
    ws[tid + 256] = Wn[tid + 256];
    ws[tid + 512] = Wn[tid + 512];
    ws[tid + 768] = Wn[tid + 768];
    __syncthreads();
    int n = blockIdx.x * 16 + (tid >> 4);   // grid = 6250 blocks, exact
    int l = tid & 15;
    if (n >= Nn) return;
    const unsigned* h32 = reinterpret_cast<const unsigned*>(hls);
    int beg = rowptr[n];
    int end = beg + deg[n];
    float a0 = 0.f, a1 = 0.f;
    for (int i = beg; i < end; i += 8) {
        int idx[8]; float msk[8];
#pragma unroll
        for (int j = 0; j < 8; ++j) {
            int k = i + j;
            int c = csr[k];                 // csr padded by 8 -> in-bounds
            bool m = (k < end);
            idx[j] = m ? c : n;
            msk[j] = m ? 1.f : 0.f;
        }
        unsigned v[8];
#pragma unroll
        for (int j = 0; j < 8; ++j) v[j] = h32[idx[j] * 16 + l];
#pragma unroll
        for (int j = 0; j < 8; ++j) {
            float lo = __uint_as_float(v[j] << 16);
            float hi = __uint_as_float(v[j] & 0xffff0000u);
            a0 = fmaf(msk[j], lo, a0);
            a1 = fmaf(msk[j], hi, a1);
        }
    }
    float di = dinv[n];
    unsigned sv = h32[n * 16 + l];
    float s0 = __uint_as_float(sv << 16);
    float s1 = __uint_as_float(sv & 0xffff0000u);
    int c0 = 2 * l, c1 = 2 * l + 1;
    float h0 = fmaxf(fmaf(di, a0 + s0, b[c0]), 0.f);
    float h1 = fmaxf(fmaf(di, a1 + s1, b[c1]), 0.f);
    // micro-GEMM: o[c] = sum_k h_k * Wn[k][c]; h_{2m},h_{2m+1} live in lane m
    float o0 = 0.f, o1 = 0.f;
#pragma unroll
    for (int m = 0; m < 16; ++m) {
        float hk0 = __shfl(h0, m, 16);
        float hk1 = __shfl(h1, m, 16);
        o0 = fmaf(hk0, ws[(2 * m) * Hh + c0], o0);
        o0 = fmaf(hk1, ws[(2 * m + 1) * Hh + c0], o0);
        o1 = fmaf(hk0, ws[(2 * m) * Hh + c1], o1);
        o1 = fmaf(hk1, ws[(2 * m + 1) * Hh + c1], o1);
    }
    __hip_bfloat162 p2;
    p2.x = f2bf(o0 * di);
    p2.y = f2bf(o1 * di);
    reinterpret_cast<__hip_bfloat162*>(hout)[n * 16 + l] = p2;
}

// ---------- final aggregation (no fused GEMM), 16 lanes/node, packed ----------
__global__ __launch_bounds__(256) void k_agg(const __hip_bfloat16* __restrict__ hls,
                                             const int* __restrict__ csr,
                                             const int* __restrict__ rowptr,
                                             const int* __restrict__ deg,
                                             const float* __restrict__ dinv,
                                             const float* __restrict__ b,
                                             __hip_bfloat16* __restrict__ hout) {
    int tid = threadIdx.x;
    int n = blockIdx.x * 16 + (tid >> 4);
    int l = tid & 15;
    if (n >= Nn) return;
    const unsigned* h32 = reinterpret_cast<const unsigned*>(hls);
    int beg = rowptr[n];
    int end = beg + deg[n];
    float a0 = 0.f, a1 = 0.f;
    for (int i = beg; i < end; i += 8) {
        int idx[8]; float msk[8];
#pragma unroll
        for (int j = 0; j < 8; ++j) {
            int k = i + j;
            int c = csr[k];
            bool m = (k < end);
            idx[j] = m ? c : n;
            msk[j] = m ? 1.f : 0.f;
        }
        unsigned v[8];
#pragma unroll
        for (int j = 0; j < 8; ++j) v[j] = h32[idx[j] * 16 + l];
#pragma unroll
        for (int j = 0; j < 8; ++j) {
            float lo = __uint_as_float(v[j] << 16);
            float hi = __uint_as_float(v[j] & 0xffff0000u);
            a0 = fmaf(msk[j], lo, a0);
            a1 = fmaf(msk[j], hi, a1);
        }
    }
    float di = dinv[n];
    unsigned sv = h32[n * 16 + l];
    float s0 = __uint_as_float(sv << 16);
    float s1 = __uint_as_float(sv & 0xffff0000u);
    float h0 = fmaxf(fmaf(di, a0 + s0, b[2 * l]), 0.f);
    float h1 = fmaxf(fmaf(di, a1 + s1, b[2 * l + 1]), 0.f);
    __hip_bfloat162 p2;
    p2.x = f2bf(h0);
    p2.y = f2bf(h1);
    reinterpret_cast<__hip_bfloat162*>(hout)[n * 16 + l] = p2;
}

// ---------- segmented mean-pool (batch is sorted), bf16 in ----------
constexpr int CH = 16;  // nodes per wave -> 6250 waves = 1563 blocks
__global__ __launch_bounds__(256) void k_pool(const __hip_bfloat16* __restrict__ h,
                                              const int* __restrict__ batch,
                                              float* __restrict__ pooled,
                                              int* __restrict__ cnt) {
    int wid = (blockIdx.x * 256 + threadIdx.x) >> 6;
    int lane = threadIdx.x & 63;
    int col = lane & 31;
    int sub = lane >> 5;
    int n0 = wid * CH;
    if (n0 >= Nn) return;
    int nEnd = min(n0 + CH, Nn);
    float acc = 0.f;
    int gcur = -1, cntLoc = 0;
    for (int n = n0 + sub; n < nEnd; n += 2) {
        int g = batch[n];
        if (g != gcur) {
            if (gcur >= 0) {
                atomAddF(&pooled[gcur * Hh + col], acc);
                if (col == 0) atomicAdd(&cnt[gcur], cntLoc);
            }
            acc = 0.f; cntLoc = 0; gcur = g;
        }
        acc += bf2f(h[(size_t)n * Hh + col]);
        cntLoc++;
    }
    if (gcur >= 0) {
        atomAddF(&pooled[gcur * Hh + col], acc);
        if (col == 0) atomicAdd(&cnt[gcur], cntLoc);
    }
}

// ---------- MLP head + log_softmax ----------
__global__ __launch_bounds__(256) void k_head(const float* __restrict__ pooled,
                                              const int* __restrict__ cnt,
                                              const float* __restrict__ Wf1,
                                              const float* __restrict__ bf1,
                                              const float* __restrict__ Wf2,
                                              const float* __restrict__ bf2,
                                              float* __restrict__ out) {
    __shared__ float w1[Hh * Hh];
    __shared__ float w2[Hh * Cc];
    __shared__ float sb1[Hh];
    __shared__ float sb2[Cc];
    int tid = threadIdx.x;
    w1[tid] = Wf1[tid]; w1[tid + 256] = Wf1[tid + 256];
    w1[tid + 512] = Wf1[tid + 512]; w1[tid + 768] = Wf1[tid + 768];
    for (int i = tid; i < Hh * Cc; i += 256) w2[i] = Wf2[i];
    if (tid < Hh) sb1[tid] = bf1[tid];
    if (tid < Cc) sb2[tid] = bf2[tid];
    __syncthreads();

    int g = tid;
    float inv = 1.0f / fmaxf((float)cnt[g], 1.0f);
    float p[Hh];
#pragma unroll
    for (int c = 0; c < Hh; ++c) p[c] = pooled[g * Hh + c] * inv;
    float h1[Hh];
#pragma unroll
    for (int j = 0; j < Hh; ++j) {
        float acc = sb1[j];
#pragma unroll
        for (int k = 0; k < Hh; ++k) acc = fmaf(p[k], w1[k * Hh + j], acc);
        h1[j] = fmaxf(acc, 0.f);
    }
    float lg[Cc];
#pragma unroll
    for (int j = 0; j < Cc; ++j) {
        float acc = sb2[j];
#pragma unroll
        for (int k = 0; k < Hh; ++k) acc = fmaf(h1[k], w2[k * Cc + j], acc);
        lg[j] = acc;
    }
    float m = lg[0];
#pragma unroll
    for (int j = 1; j < Cc; ++j) m = fmaxf(m, lg[j]);
    float s = 0.f;
#pragma unroll
    for (int j = 0; j < Cc; ++j) s += __expf(lg[j] - m);
    float lse = m + __logf(s);
#pragma unroll
    for (int j = 0; j < Cc; ++j) out[g * Cc + j] = lg[j] - lse;
}

extern "C" void kernel_launch(void* const* d_in, const int* in_sizes, int n_in,
                              void* d_out, int out_size, void* d_ws, size_t ws_size,
                              hipStream_t stream) {
    const float* x    = (const float*)d_in[0];
    const int*   ei   = (const int*)d_in[1];   // [2, E] -> src = ei, dst = ei + E
    const int*   batch= (const int*)d_in[2];
    const float* W1   = (const float*)d_in[3];
    const float* b1   = (const float*)d_in[4];
    const float* W2   = (const float*)d_in[5];
    const float* b2   = (const float*)d_in[6];
    const float* W3   = (const float*)d_in[7];
    const float* b3   = (const float*)d_in[8];
    const float* W4   = (const float*)d_in[9];
    const float* b4   = (const float*)d_in[10];
    const float* Wf1  = (const float*)d_in[11];
    const float* bf1  = (const float*)d_in[12];
    const float* Wf2  = (const float*)d_in[13];
    const float* bf2  = (const float*)d_in[14];
    float* out = (float*)d_out;

    const int* src = ei;
    const int* dst = ei + Ee;

    // Workspace layout (8B-aligned first)
    char* ws = (char*)d_ws;
    int2*  bucket = (int2*)ws;    ws += sizeof(int2) * Ee;                   // 12.8 MB
    __hip_bfloat16* hl   = (__hip_bfloat16*)ws; ws += sizeof(__hip_bfloat16) * Nn * Hh;  // 6.4 MB
    __hip_bfloat16* hbuf = (__hip_bfloat16*)ws; ws += sizeof(__hip_bfloat16) * Nn * Hh;  // 6.4 MB
    int*   csr    = (int*)ws;     ws += sizeof(int) * (Ee + 8);              // +8 pad
    int*   M      = (int*)ws;     ws += sizeof(int) * NCH * NR;              // 306 KB
    int*   T      = (int*)ws;     ws += sizeof(int) * NR;
    int*   R      = (int*)ws;     ws += sizeof(int) * (NR + 1);
    int*   rowptr = (int*)ws;     ws += sizeof(int) * Nn;
    int*   deg    = (int*)ws;     ws += sizeof(int) * Nn;
    float* dinv   = (float*)ws;   ws += sizeof(float) * Nn;
    float* pooled = (float*)ws;   ws += sizeof(float) * Gg * Hh;
    int*   cnt    = (int*)ws;     ws += sizeof(int) * Gg;

    const int nbNode16 = (Nn + 15) / 16;                   // 6250
    const int nbTile   = (Nn + TM - 1) / TM;               // 1563

    // ---- graph preprocessing: counting sort -> CSR, deg, dinv, rowptr ----
    k_count <<<NCH, 512, 0, stream>>>(dst, M);
    k_scanM <<<NR, 256, 0, stream>>>(M, T);
    k_scanT <<<1, 512, 0, stream>>>(T, R);
    k_bucket<<<NCH, 512, 0, stream>>>(src, dst, M, R, bucket);
    k_build <<<NR, 512, 0, stream>>>(bucket, R, csr, rowptr, deg, dinv);

    // ---- layer 1 GEMM ----
    k_gemm128<<<nbTile, 256, 0, stream>>>(x, W1, dinv, hl);

    // ---- layers 1..3 aggregation fused with next layer's GEMM ----
    k_aggemm<<<nbNode16, 256, 0, stream>>>(hl, csr, rowptr, deg, dinv, b1, W2, hbuf);
    k_aggemm<<<nbNode16, 256, 0, stream>>>(hbuf, csr, rowptr, deg, dinv, b2, W3, hl);
    k_aggemm<<<nbNode16, 256, 0, stream>>>(hl, csr, rowptr, deg, dinv, b3, W4, hbuf);

    // ---- layer 4 aggregation (final h) ----
    k_agg<<<nbNode16, 256, 0, stream>>>(hbuf, csr, rowptr, deg, dinv, b4, hl);

    // ---- pool + head ----
    hipMemsetAsync(pooled, 0, sizeof(float) * Gg * Hh, stream);
    hipMemsetAsync(cnt, 0, sizeof(int) * Gg, stream);
    {
        int waves = (Nn + CH - 1) / CH;               // 6250
        int blocks = (waves * 64 + 255) / 256;        // 1563
        k_pool<<<blocks, 256, 0, stream>>>(hl, batch, pooled, cnt);
    }
    k_head<<<1, 256, 0, stream>>>(pooled, cnt, Wf1, bf1, Wf2, bf2, out);
}